// Round 10
// baseline (1997.918 us; speedup 1.0000x reference)
//
#include <hip/hip_runtime.h>
#include <stdint.h>

// ---------------------------------------------------------------------------
// JAX threefry2x32 (20 rounds), matching jax/_src/prng.py
// ---------------------------------------------------------------------------
struct SnnKeys { unsigned int k0[30]; unsigned int k1[30]; };

__host__ __device__ static inline void tf2x32(unsigned int k0, unsigned int k1,
                                              unsigned int& x0, unsigned int& x1) {
  unsigned int ks2 = k0 ^ k1 ^ 0x1BD11BDAu;
#define TF_RND(r) { x0 += x1; x1 = (x1 << (r)) | (x1 >> (32 - (r))); x1 ^= x0; }
  x0 += k0; x1 += k1;
  TF_RND(13) TF_RND(15) TF_RND(26) TF_RND(6)
  x0 += k1; x1 += ks2 + 1u;
  TF_RND(17) TF_RND(29) TF_RND(16) TF_RND(24)
  x0 += ks2; x1 += k0 + 2u;
  TF_RND(13) TF_RND(15) TF_RND(26) TF_RND(6)
  x0 += k0; x1 += k1 + 3u;
  TF_RND(17) TF_RND(29) TF_RND(16) TF_RND(24)
  x0 += k1; x1 += ks2 + 4u;
  TF_RND(13) TF_RND(15) TF_RND(26) TF_RND(6)
  x0 += ks2; x1 += k0 + 5u;
#undef TF_RND
}

// ---------------------------------------------------------------------------
// Stage 0: 2x2 average pool  x(4,24,602,602) -> xp(4,24,301,301)
// ---------------------------------------------------------------------------
#define POOL_N (4 * 24 * 301 * 301)

__global__ __launch_bounds__(256) void k_pool(const float* __restrict__ x,
                                              float* __restrict__ xp) {
  int i = blockIdx.x * 256 + threadIdx.x;
  if (i >= POOL_N) return;
  int j = i % 301;
  int rest = i / 301;
  int r = rest % 301;
  int bc = rest / 301;
  const float* src = x + ((size_t)bc * 602 + 2 * r) * 602 + 2 * j;
  float2 a = *(const float2*)src;
  float2 b = *(const float2*)(src + 602);
  xp[i] = 0.25f * ((a.x + a.y) + (b.x + b.y));
}

// ---------------------------------------------------------------------------
// weight transposes: [co][ci][kd][kh][kw] -> [ci][kd][kh][kw][co]
// ---------------------------------------------------------------------------
__global__ __launch_bounds__(256) void k_wt2(const float* __restrict__ w2,
                                             float* __restrict__ w2t) {
  int i = blockIdx.x * 256 + threadIdx.x;
  if (i >= 345600) return;
  int co = i & 31;
  int rest = i >> 5;            // ci*675 + kd*225 + k
  int ci = rest / 675;
  int k675 = rest - ci * 675;
  w2t[i] = w2[((size_t)co * 16 + ci) * 675 + k675];
}

__global__ __launch_bounds__(256) void k_wt3(const float* __restrict__ w3,
                                             float* __restrict__ w3t) {
  int i = blockIdx.x * 256 + threadIdx.x;
  if (i >= 345600) return;
  int co = i & 15;
  int rest = i >> 4;            // ci*675 + kd*225 + k
  int ci = rest / 675;
  int k675 = rest - ci * 675;
  w3t[i] = w3[((size_t)co * 32 + ci) * 675 + k675];
}

// ---------------------------------------------------------------------------
// conv1 (R1 original): xp(4,[1],24,301,301), w1(16,1,3,15,15), stride2
// -> h1(4,16,11,144,144), relu.  grid (41 stile of 512 s, 44 b*d).
// 4 waves = 2 co-groups(8co) x 2 s-groups(256 s). Weights via SGPR loads.
// ---------------------------------------------------------------------------
__global__ __launch_bounds__(256) void k_conv1(const float* __restrict__ xp,
                                               const float* __restrict__ w1,
                                               const float* __restrict__ b1,
                                               float* __restrict__ h1) {
  __shared__ alignas(16) float in_e[25 * 152];
  __shared__ alignas(16) float in_o[25 * 152];
  const int tid = threadIdx.x;
  const int wave = __builtin_amdgcn_readfirstlane(tid >> 6);
  const int lane = tid & 63;
  const int cog = wave >> 1, sg = wave & 1;
  const int cob = cog * 8;
  const int bz = blockIdx.y;
  const int b = bz / 11, d = bz % 11;
  const int s0 = blockIdx.x * 512;
  const int y0 = s0 / 144;

  int sq[4], be[4];
  bool vq[4];
#pragma unroll
  for (int q = 0; q < 4; ++q) {
    int s = s0 + sg * 256 + q * 64 + lane;
    vq[q] = (s < 20736);
    int sc = vq[q] ? s : 20735;
    int y = sc / 144, xx = sc - y * 144;
    sq[q] = s;
    be[q] = 2 * (y - y0) * 152 + xx;
  }

  float acc[8][4] = {};

  for (int kd = 0; kd < 3; ++kd) {
    __syncthreads();
    const int din = 2 * d + kd;
    const float* src = xp + (size_t)(b * 24 + din) * 90601;
    for (int i = tid; i < 25 * 301; i += 256) {
      int r = i / 301, c = i - r * 301;
      int gr = 2 * y0 + r;
      float v = (gr < 301) ? src[gr * 301 + c] : 0.0f;
      ((c & 1) ? in_o : in_e)[r * 152 + (c >> 1)] = v;
    }
    __syncthreads();
    const float* wp = w1 + cob * 675 + kd * 225;   // wp[c*675 + kh*15 + kw], uniform
    for (int kh = 0; kh < 15; ++kh) {
      float e[4][8], o[4][7];
#pragma unroll
      for (int q = 0; q < 4; ++q) {
        const float* pe = in_e + be[q] + kh * 152;
        const float* po = in_o + be[q] + kh * 152;
#pragma unroll
        for (int j = 0; j < 8; ++j) e[q][j] = pe[j];
#pragma unroll
        for (int j = 0; j < 7; ++j) o[q][j] = po[j];
      }
      const float* wk = wp + kh * 15;
#pragma unroll
      for (int j = 0; j < 8; ++j) {
#pragma unroll
        for (int c = 0; c < 8; ++c) {
          float wv = wk[c * 675 + 2 * j];
#pragma unroll
          for (int q = 0; q < 4; ++q) acc[c][q] += wv * e[q][j];
        }
      }
#pragma unroll
      for (int j = 0; j < 7; ++j) {
#pragma unroll
        for (int c = 0; c < 8; ++c) {
          float wv = wk[c * 675 + 2 * j + 1];
#pragma unroll
          for (int q = 0; q < 4; ++q) acc[c][q] += wv * o[q][j];
        }
      }
    }
  }
#pragma unroll
  for (int q = 0; q < 4; ++q) {
    if (vq[q]) {
#pragma unroll
      for (int c = 0; c < 8; ++c) {
        float v = acc[c][q] + b1[cob + c];
        h1[((size_t)(b * 16 + cob + c) * 11 + d) * 20736 + sq[q]] = fmaxf(v, 0.0f);
      }
    }
  }
}

// ---------------------------------------------------------------------------
// conv2 v5: h1(4,16,11,144,144), w2t[ci][kd][k][32] -> 3 partials
// v4 compute structure + DOUBLE-BUFFERED LDS + register prefetch (T14/T3):
// one barrier per stage (16 total, was 32); stage s+1 global loads issued
// before stage s compute -> HBM/L2 latency hidden under 15-kh FMA phase.
// grid (18, 60) = 1080 blocks.
// ---------------------------------------------------------------------------
__global__ __launch_bounds__(256) void k_conv2(const float* __restrict__ h1,
                                               const float* __restrict__ w2t,
                                               float* __restrict__ h2p) {
  __shared__ alignas(16) float in_e[2][23 * 76];
  __shared__ alignas(16) float in_o[2][23 * 76];
  const int tid = threadIdx.x;
  const int wave = __builtin_amdgcn_readfirstlane(tid >> 6);
  const int lane = tid & 63;
  const int cob = wave * 8;
  const int bz = blockIdx.y;
  const int cig3 = bz % 3;
  const int t5 = bz / 3;
  const int b = t5 / 5, d = t5 % 5;
  const int g0 = blockIdx.x * 64;          // gi base (gi = r*17 + g)
  const int r0 = g0 / 17;
  const int row0 = 2 * r0;

  const int gi0 = g0 + lane;
  const bool valid = (gi0 < 1105);
  const int gi = valid ? gi0 : 1104;
  const int r = gi / 17;
  const int g = gi - r * 17;
  const int lr = r - r0;                   // 0..4
  const int x0 = g * 4;

  float acc[8][4] = {};
  float4 pre[4];

  auto issue = [&](int st) {
    const int u = cig3 * 16 + st;
    const int ci = u / 3;
    const int kd = u - 3 * ci;
    const int din = 2 * d + kd;
    const float* src = h1 + (size_t)((b * 16 + ci) * 11 + din) * 20736;
#pragma unroll
    for (int ii = 0; ii < 4; ++ii) {
      int i = tid + ii * 256;
      float4 v = {0.0f, 0.0f, 0.0f, 0.0f};
      if (i < 828) {                        // 828 = 23*36
        int irr = i / 36, c4 = i - irr * 36;
        int gr = row0 + irr;
        if (gr < 144) v = *(const float4*)(src + gr * 144 + c4 * 4);
      }
      pre[ii] = v;
    }
  };

  auto write_lds = [&](int buf) {
#pragma unroll
    for (int ii = 0; ii < 4; ++ii) {
      int i = tid + ii * 256;
      if (i < 828) {
        int irr = i / 36, c4 = i - irr * 36;
        int off = irr * 76 + 2 * c4;
        float4 v = pre[ii];
        *(float2*)&in_e[buf][off] = make_float2(v.x, v.z);
        *(float2*)&in_o[buf][off] = make_float2(v.y, v.w);
      }
    }
  };

  issue(0);
  write_lds(0);
  __syncthreads();

  for (int st = 0; st < 16; ++st) {
    const int cur = st & 1;
    if (st < 15) issue(st + 1);            // global loads overlap compute below

    const int u = cig3 * 16 + st;
    const int ci = u / 3;
    const int kd = u - 3 * ci;
    const float* wkb = w2t + (size_t)(ci * 3 + kd) * 225 * 32 + cob;  // uniform
    const float* pe0 = &in_e[cur][2 * lr * 76 + x0];
    const float* po0 = &in_o[cur][2 * lr * 76 + x0];
#pragma unroll 5
    for (int kh = 0; kh < 15; ++kh) {
      float4 e0 = *(const float4*)(pe0 + kh * 76);
      float4 e1 = *(const float4*)(pe0 + kh * 76 + 4);
      float4 e2 = *(const float4*)(pe0 + kh * 76 + 8);
      float4 o0 = *(const float4*)(po0 + kh * 76);
      float4 o1 = *(const float4*)(po0 + kh * 76 + 4);
      float4 o2 = *(const float4*)(po0 + kh * 76 + 8);
      float E[12] = {e0.x, e0.y, e0.z, e0.w, e1.x, e1.y, e1.z, e1.w,
                     e2.x, e2.y, e2.z, e2.w};
      float O[12] = {o0.x, o0.y, o0.z, o0.w, o1.x, o1.y, o1.z, o1.w,
                     o2.x, o2.y, o2.z, o2.w};
      const float* wk = wkb + kh * 480;     // 15 taps * 32 co
#pragma unroll
      for (int m = 0; m < 8; ++m) {         // even kw = 2m
#pragma unroll
        for (int c = 0; c < 8; ++c) {
          float wv = wk[m * 64 + c];
#pragma unroll
          for (int u2 = 0; u2 < 4; ++u2) acc[c][u2] += wv * E[m + u2];
        }
      }
#pragma unroll
      for (int m = 0; m < 7; ++m) {         // odd kw = 2m+1
#pragma unroll
        for (int c = 0; c < 8; ++c) {
          float wv = wk[m * 64 + 32 + c];
#pragma unroll
          for (int u2 = 0; u2 < 4; ++u2) acc[c][u2] += wv * O[m + u2];
        }
      }
    }
    if (st < 15) {
      write_lds(cur ^ 1);                  // other buffer: no read/write overlap
      __syncthreads();                     // single barrier per stage
    }
  }
  if (valid) {
    float* dst = h2p + (size_t)cig3 * 2704000 +
                 ((size_t)(b * 32 + cob) * 5 + d) * 4225 + r * 65 + x0;
#pragma unroll
    for (int c = 0; c < 8; ++c) {
#pragma unroll
      for (int u = 0; u < 4; ++u) {
        if (x0 + u < 65) dst[(size_t)c * 21125 + u] = acc[c][u];
      }
    }
  }
}

// combine conv2 partials (3) + bias + relu
__global__ __launch_bounds__(256) void k_h2fix(const float* __restrict__ p,
                                               const float* __restrict__ b2,
                                               float* __restrict__ h2) {
  int i = blockIdx.x * 256 + threadIdx.x;
  if (i >= 2704000) return;
  int co = (i / 21125) & 31;               // 21125 = 5*65*65
  float v = p[i] + p[2704000 + i] + p[5408000 + i] + b2[co];
  h2[i] = fmaxf(v, 0.0f);
}

// ---------------------------------------------------------------------------
// conv3: h2(4,32,5,65,65), w3t[ci][kd][k][16] -> 32 ci-partials
// Flattened-s: plane 26*26=676 per (b,d). grid (2 stile of 512, 8 planes, 32 ci).
// 4 waves = 2 co-groups(8co) x 2 s-groups(256 s). 512 blocks (2/CU).
// ---------------------------------------------------------------------------
__global__ __launch_bounds__(256) void k_conv3(const float* __restrict__ h2,
                                               const float* __restrict__ w3t,
                                               float* __restrict__ h3p) {
  __shared__ alignas(16) float in_e[55 * 36];
  __shared__ alignas(16) float in_o[55 * 36];
  const int tid = threadIdx.x;
  const int wave = __builtin_amdgcn_readfirstlane(tid >> 6);
  const int lane = tid & 63;
  const int cog = wave >> 1, sg = wave & 1;
  const int cob = cog * 8;
  const int bz = blockIdx.y;               // b*2 + d
  const int b = bz >> 1, d = bz & 1;
  const int ci = blockIdx.z;               // 0..31
  const int s0 = blockIdx.x * 512;
  const int y0 = s0 / 26;

  int sq[4], be[4];
  bool vq[4];
#pragma unroll
  for (int q = 0; q < 4; ++q) {
    int s = s0 + sg * 256 + q * 64 + lane;
    vq[q] = (s < 676);
    int sc = vq[q] ? s : 675;
    int y = sc / 26, xx = sc - y * 26;
    sq[q] = s;
    be[q] = 2 * (y - y0) * 36 + xx;
  }

  float acc[8][4] = {};

  for (int kd = 0; kd < 3; ++kd) {
    __syncthreads();
    const int din = 2 * d + kd;
    const float* src = h2 + (size_t)((b * 32 + ci) * 5 + din) * 4225;
    for (int i = tid; i < 55 * 65; i += 256) {
      int r = i / 65, c = i - r * 65;
      int gr = 2 * y0 + r;
      float v = (gr < 65) ? src[gr * 65 + c] : 0.0f;
      ((c & 1) ? in_o : in_e)[r * 36 + (c >> 1)] = v;
    }
    __syncthreads();
    const float* wkbase = w3t + (size_t)(ci * 3 + kd) * 225 * 16 + cob;  // uniform
    for (int kh = 0; kh < 15; ++kh) {
      float e[4][8], o[4][7];
#pragma unroll
      for (int q = 0; q < 4; ++q) {
        const float* pe = in_e + be[q] + kh * 36;
        const float* po = in_o + be[q] + kh * 36;
#pragma unroll
        for (int j = 0; j < 8; ++j) e[q][j] = pe[j];
#pragma unroll
        for (int j = 0; j < 7; ++j) o[q][j] = po[j];
      }
      const float* wr = wkbase + kh * 15 * 16;
#pragma unroll
      for (int j = 0; j < 8; ++j) {
#pragma unroll
        for (int c = 0; c < 8; ++c) {
          float wv = wr[(2 * j) * 16 + c];
#pragma unroll
          for (int q = 0; q < 4; ++q) acc[c][q] += wv * e[q][j];
        }
      }
#pragma unroll
      for (int j = 0; j < 7; ++j) {
#pragma unroll
        for (int c = 0; c < 8; ++c) {
          float wv = wr[(2 * j + 1) * 16 + c];
#pragma unroll
          for (int q = 0; q < 4; ++q) acc[c][q] += wv * o[q][j];
        }
      }
    }
  }
#pragma unroll
  for (int q = 0; q < 4; ++q) {
    if (vq[q]) {
#pragma unroll
      for (int c = 0; c < 8; ++c) {
        h3p[(size_t)ci * 86528 +
            ((size_t)(b * 16 + cob + c) * 2 + d) * 676 + sq[q]] = acc[c][q];
      }
    }
  }
}

// fold 32 conv3 partials + bias + relu -> prob = 0.5*x
__global__ __launch_bounds__(256) void k_h3fix(const float* __restrict__ h3p,
                                               const float* __restrict__ b3,
                                               float* __restrict__ prob) {
  int p = blockIdx.x * 256 + threadIdx.x;
  if (p >= 86528) return;
  int co = (p % 21632) / 1352;             // 1352 = 2*26*26
  float x = b3[co];
  for (int g = 0; g < 32; ++g) x += h3p[(size_t)g * 86528 + p];
  prob[p] = 0.5f * fmaxf(x, 0.0f);
}

// ---------------------------------------------------------------------------
// spikes: r = threefry-uniform; spk = (prob > r)
// grid (338, 30) block 256
// ---------------------------------------------------------------------------
__global__ __launch_bounds__(256) void k_spike(const float* __restrict__ prob,
                                               float* __restrict__ spk,
                                               SnnKeys keys) {
  int p = blockIdx.x * 256 + threadIdx.x;   // < 86528
  int t = blockIdx.y;
  float pr = prob[p];
  unsigned int x0 = 0u, x1 = (unsigned int)p;
  tf2x32(keys.k0[t], keys.k1[t], x0, x1);
  unsigned int bits = x0 ^ x1;              // partitionable 32-bit path
  float r = __uint_as_float((bits >> 9) | 0x3f800000u) - 1.0f;
  spk[(size_t)t * 86528 + p] = (pr > r) ? 1.0f : 0.0f;
}

// ---------------------------------------------------------------------------
// fc1 GEMM: inc_part[kc][m=(t*4+b)][n] = sum_k spk[m][k]*fc1_w[n][k]  (K split 26x832)
// grid (16 nt, 26 kc), block (8,16)=128. thread tile 8m x 4n.
// ---------------------------------------------------------------------------
__global__ __launch_bounds__(128) void k_fc1(const float* __restrict__ spk,
                                             const float* __restrict__ fc1w,
                                             float* __restrict__ incp) {
  __shared__ alignas(16) float slds[16][128];
  __shared__ alignas(16) float wlds[16][32];
  const int tx = threadIdx.x;               // 0..7
  const int ty = threadIdx.y;               // 0..15
  const int tid = ty * 8 + tx;
  const int nt = blockIdx.x;                // 0..15
  const int kc = blockIdx.y;                // 0..25
  const int k0base = kc * 832;

  float acc[8][4];
#pragma unroll
  for (int mi = 0; mi < 8; ++mi)
#pragma unroll
    for (int ni = 0; ni < 4; ++ni) acc[mi][ni] = 0.0f;

  for (int kb = 0; kb < 832; kb += 16) {
    const int k0 = k0base + kb;
    __syncthreads();
    {
      int m = tid;  // 0..127
      float4 v[4] = {{0,0,0,0},{0,0,0,0},{0,0,0,0},{0,0,0,0}};
      if (m < 120) {
        const float4* s = (const float4*)(spk + (size_t)m * 21632 + k0);
        v[0] = s[0]; v[1] = s[1]; v[2] = s[2]; v[3] = s[3];
      }
#pragma unroll
      for (int q = 0; q < 4; ++q) {
        slds[4 * q + 0][m] = v[q].x;
        slds[4 * q + 1][m] = v[q].y;
        slds[4 * q + 2][m] = v[q].z;
        slds[4 * q + 3][m] = v[q].w;
      }
    }
    for (int e = tid; e < 512; e += 128) {
      int n = e >> 4, kk = e & 15;
      wlds[kk][n] = fc1w[(size_t)(nt * 32 + n) * 21632 + k0 + kk];
    }
    __syncthreads();
#pragma unroll
    for (int kk = 0; kk < 16; ++kk) {
      const float4 wv = *(const float4*)&wlds[kk][tx * 4];
      const float4 s0 = *(const float4*)&slds[kk][ty * 8];
      const float4 s1 = *(const float4*)&slds[kk][ty * 8 + 4];
      float sv[8] = {s0.x, s0.y, s0.z, s0.w, s1.x, s1.y, s1.z, s1.w};
      float wz[4] = {wv.x, wv.y, wv.z, wv.w};
#pragma unroll
      for (int mi = 0; mi < 8; ++mi)
#pragma unroll
        for (int ni = 0; ni < 4; ++ni) acc[mi][ni] += sv[mi] * wz[ni];
    }
  }
#pragma unroll
  for (int mi = 0; mi < 8; ++mi) {
    int m = ty * 8 + mi;
    if (m < 120) {
      float4 o = {acc[mi][0], acc[mi][1], acc[mi][2], acc[mi][3]};
      *(float4*)&incp[((size_t)kc * 120 + m) * 512 + nt * 32 + tx * 4] = o;
    }
  }
}

// ---------------------------------------------------------------------------
// sequential membrane scan per (b,n): fire/reset, emit spike counts
// ---------------------------------------------------------------------------
__global__ __launch_bounds__(256) void k_scan(const float* __restrict__ incp,
                                              const float* __restrict__ fc1b,
                                              float* __restrict__ cnt) {
  int i = blockIdx.x * 256 + threadIdx.x;   // 0..2047
  int b = i >> 9, n = i & 511;
  float bias = fc1b[n];
  float m0 = 0.0f, c = 0.0f;
  for (int t = 0; t < 30; ++t) {
    int m = t * 4 + b;
    float s = bias;
    for (int kc = 0; kc < 26; ++kc) s += incp[((size_t)kc * 120 + m) * 512 + n];
    m0 += s;
    if (m0 > 1.0f) { c += 1.0f; m0 = 0.0f; }
  }
  cnt[i] = c;
}

// ---------------------------------------------------------------------------
// m1[b][o] = 30*fc2_b[o] + sum_n cnt[b][n]*fc2_w[o][n]
// ---------------------------------------------------------------------------
__global__ __launch_bounds__(256) void k_final(const float* __restrict__ cnt,
                                               const float* __restrict__ fc2w,
                                               const float* __restrict__ fc2b,
                                               float* __restrict__ out) {
  int o = threadIdx.x;
  if (o >= 216) return;
  int b = o / 54, oo = o - b * 54;
  const float* w = fc2w + (size_t)oo * 512;
  const float* c = cnt + (size_t)b * 512;
  float s = 0.0f;
  for (int n = 0; n < 512; ++n) s += c[n] * w[n];
  out[o] = s + 30.0f * fc2b[oo];
}

// ---------------------------------------------------------------------------
extern "C" void kernel_launch(void* const* d_in, const int* in_sizes, int n_in,
                              void* d_out, int out_size, void* d_ws, size_t ws_size,
                              hipStream_t stream) {
  (void)in_sizes; (void)n_in; (void)out_size; (void)ws_size;
  const float* x    = (const float*)d_in[0];
  const float* w1   = (const float*)d_in[1];
  const float* b1   = (const float*)d_in[2];
  const float* w2   = (const float*)d_in[3];
  const float* b2   = (const float*)d_in[4];
  const float* w3   = (const float*)d_in[5];
  const float* b3   = (const float*)d_in[6];
  const float* fc1w = (const float*)d_in[7];
  const float* fc1b = (const float*)d_in[8];
  const float* fc2w = (const float*)d_in[9];
  const float* fc2b = (const float*)d_in[10];
  float* out = (float*)d_out;
  float* ws  = (float*)d_ws;

  // workspace layout (floats); peak = xp+h1 = 23,295,840 fl = 93.2 MB (unchanged)
  float* xp   = ws;                       // [0 .. 8,697,696)            dead after conv1
  float* h1   = ws + 8697696;             // [8,697,696 .. 23,295,840)   dead after conv2
  float* w2t  = ws + 8112000;             // 345,600 in dead-xp tail [8,112,000..8,457,600)
  float* h2p  = ws;                       // 3 x 2,704,000 = [0 .. 8,112,000)
  float* h2   = ws + 8697696;             // [8,697,696 .. 11,401,696)  (dead h1 region)
  float* w3t  = ws;                       // 345,600 (in dead h2p; written after h2fix)
  float* h3p  = ws + 11401696;            // 32 x 86,528 = [11,401,696 .. 14,170,592)
  float* prob = ws + 14170592;            // 86,528 -> 14,257,120
  float* spk  = ws + 14257120;            // 2,595,840 -> 16,852,960
  float* incp = ws + 16852960;            // 26 x 61,440 -> 18,450,400
  float* cnt  = ws + 18450400;            // 2,048 (end 18,452,448 < 23,295,840)

  // host-side threefry: seed 42 -> key (0,42); partitionable split
  SnnKeys keys;
  for (int t = 0; t < 30; ++t) {
    unsigned int a = 0u, bb = (unsigned int)t;
    tf2x32(0u, 42u, a, bb);
    keys.k0[t] = a; keys.k1[t] = bb;
  }

  k_pool <<<(POOL_N + 255) / 256, 256, 0, stream>>>(x, xp);
  k_conv1<<<dim3(41, 44),    256, 0, stream>>>(xp, w1, b1, h1);
  k_wt2  <<<1350, 256, 0, stream>>>(w2, w2t);
  k_conv2<<<dim3(18, 60),    256, 0, stream>>>(h1, w2t, h2p);
  k_h2fix<<<(2704000 + 255) / 256, 256, 0, stream>>>(h2p, b2, h2);
  k_wt3  <<<1350, 256, 0, stream>>>(w3, w3t);
  k_conv3<<<dim3(2, 8, 32),  256, 0, stream>>>(h2, w3t, h3p);
  k_h3fix<<<338, 256, 0, stream>>>(h3p, b3, prob);
  k_spike<<<dim3(338, 30),   256, 0, stream>>>(prob, spk, keys);
  k_fc1  <<<dim3(16, 26), dim3(8, 16), 0, stream>>>(spk, fc1w, incp);
  k_scan <<<8, 256, 0, stream>>>(incp, fc1b, cnt);
  k_final<<<1, 256, 0, stream>>>(cnt, fc2w, fc2b, out);
}

// Round 11
// 1839.321 us; speedup vs baseline: 1.0862x; 1.0862x over previous
//
#include <hip/hip_runtime.h>
#include <stdint.h>

// ---------------------------------------------------------------------------
// JAX threefry2x32 (20 rounds), matching jax/_src/prng.py
// ---------------------------------------------------------------------------
struct SnnKeys { unsigned int k0[30]; unsigned int k1[30]; };

__host__ __device__ static inline void tf2x32(unsigned int k0, unsigned int k1,
                                              unsigned int& x0, unsigned int& x1) {
  unsigned int ks2 = k0 ^ k1 ^ 0x1BD11BDAu;
#define TF_RND(r) { x0 += x1; x1 = (x1 << (r)) | (x1 >> (32 - (r))); x1 ^= x0; }
  x0 += k0; x1 += k1;
  TF_RND(13) TF_RND(15) TF_RND(26) TF_RND(6)
  x0 += k1; x1 += ks2 + 1u;
  TF_RND(17) TF_RND(29) TF_RND(16) TF_RND(24)
  x0 += ks2; x1 += k0 + 2u;
  TF_RND(13) TF_RND(15) TF_RND(26) TF_RND(6)
  x0 += k0; x1 += k1 + 3u;
  TF_RND(17) TF_RND(29) TF_RND(16) TF_RND(24)
  x0 += k1; x1 += ks2 + 4u;
  TF_RND(13) TF_RND(15) TF_RND(26) TF_RND(6)
  x0 += ks2; x1 += k0 + 5u;
#undef TF_RND
}

// ---------------------------------------------------------------------------
// Stage 0: 2x2 average pool  x(4,24,602,602) -> xp(4,24,301,301)
// ---------------------------------------------------------------------------
#define POOL_N (4 * 24 * 301 * 301)

__global__ __launch_bounds__(256) void k_pool(const float* __restrict__ x,
                                              float* __restrict__ xp) {
  int i = blockIdx.x * 256 + threadIdx.x;
  if (i >= POOL_N) return;
  int j = i % 301;
  int rest = i / 301;
  int r = rest % 301;
  int bc = rest / 301;
  const float* src = x + ((size_t)bc * 602 + 2 * r) * 602 + 2 * j;
  float2 a = *(const float2*)src;
  float2 b = *(const float2*)(src + 602);
  xp[i] = 0.25f * ((a.x + a.y) + (b.x + b.y));
}

// ---------------------------------------------------------------------------
// weight transposes: [co][ci][kd][kh][kw] -> [ci][kd][kh][kw][co]
// ---------------------------------------------------------------------------
__global__ __launch_bounds__(256) void k_wt2(const float* __restrict__ w2,
                                             float* __restrict__ w2t) {
  int i = blockIdx.x * 256 + threadIdx.x;
  if (i >= 345600) return;
  int co = i & 31;
  int rest = i >> 5;            // ci*675 + kd*225 + k
  int ci = rest / 675;
  int k675 = rest - ci * 675;
  w2t[i] = w2[((size_t)co * 16 + ci) * 675 + k675];
}

__global__ __launch_bounds__(256) void k_wt3(const float* __restrict__ w3,
                                             float* __restrict__ w3t) {
  int i = blockIdx.x * 256 + threadIdx.x;
  if (i >= 345600) return;
  int co = i & 15;
  int rest = i >> 4;            // ci*675 + kd*225 + k
  int ci = rest / 675;
  int k675 = rest - ci * 675;
  w3t[i] = w3[((size_t)co * 32 + ci) * 675 + k675];
}

// ---------------------------------------------------------------------------
// conv1 v4: xp(4,[1],24,301,301), w1(16,1,3,15,15), s2 -> h1(4,16,11,144,144)
// conv2-v2 structure with 18-LANE row groups (conflict fix vs v3's 36-lane):
// half-rows h in {0,1}, gi = y*36 + h*18 + g (g=0..17), x0 = h*72 + 4g.
// Lane owns 4 consecutive x; 3+3 aligned immediate-offset b128 reads per kh.
// grid (41, 44). 4 waves = 2 co-groups(8co) x 2 gi-groups(64).
// ---------------------------------------------------------------------------
__global__ __launch_bounds__(256) void k_conv1(const float* __restrict__ xp,
                                               const float* __restrict__ w1,
                                               const float* __restrict__ b1,
                                               float* __restrict__ h1) {
  __shared__ alignas(16) float in_e[23 * 152];
  __shared__ alignas(16) float in_o[23 * 152];
  const int tid = threadIdx.x;
  const int wave = __builtin_amdgcn_readfirstlane(tid >> 6);
  const int lane = tid & 63;
  const int cog = wave >> 1, sg = wave & 1;
  const int cob = cog * 8;
  const int bz = blockIdx.y;
  const int b = bz / 11, d = bz % 11;
  const int g0 = blockIdx.x * 128;         // 128 gi per block (2 sg halves)
  const int y0 = g0 / 36;
  const int row0 = 2 * y0;

  const int gi0 = g0 + sg * 64 + lane;
  const bool valid = (gi0 < 5184);
  const int gi = valid ? gi0 : 5183;
  const int y = gi / 36;
  const int rem = gi - y * 36;
  const int h = rem / 18;
  const int g = rem - h * 18;
  const int lr = y - y0;                   // 0..4
  const int x0 = h * 72 + g * 4;           // 4-aligned -> b128-aligned reads

  float acc[8][4] = {};

  for (int kd = 0; kd < 3; ++kd) {
    __syncthreads();
    const int din = 2 * d + kd;
    const float* src = xp + (size_t)(b * 24 + din) * 90601;
    for (int i = tid; i < 23 * 301; i += 256) {
      int irr = i / 301, c = i - irr * 301;
      int gr = row0 + irr;
      float v = (gr < 301) ? src[gr * 301 + c] : 0.0f;
      ((c & 1) ? in_o : in_e)[irr * 152 + (c >> 1)] = v;
    }
    __syncthreads();
    const float* wp = w1 + cob * 675 + kd * 225;   // uniform (SGPR loads)
    const float* pe0 = in_e + 2 * lr * 152 + x0;
    const float* po0 = in_o + 2 * lr * 152 + x0;
#pragma unroll 5
    for (int kh = 0; kh < 15; ++kh) {
      float4 e0 = *(const float4*)(pe0 + kh * 152);
      float4 e1 = *(const float4*)(pe0 + kh * 152 + 4);
      float4 e2 = *(const float4*)(pe0 + kh * 152 + 8);
      float4 o0 = *(const float4*)(po0 + kh * 152);
      float4 o1 = *(const float4*)(po0 + kh * 152 + 4);
      float4 o2 = *(const float4*)(po0 + kh * 152 + 8);
      float E[12] = {e0.x, e0.y, e0.z, e0.w, e1.x, e1.y, e1.z, e1.w,
                     e2.x, e2.y, e2.z, e2.w};
      float O[12] = {o0.x, o0.y, o0.z, o0.w, o1.x, o1.y, o1.z, o1.w,
                     o2.x, o2.y, o2.z, o2.w};
      const float* wk = wp + kh * 15;
#pragma unroll
      for (int m = 0; m < 8; ++m) {        // even kw = 2m
#pragma unroll
        for (int c = 0; c < 8; ++c) {
          float wv = wk[c * 675 + 2 * m];
#pragma unroll
          for (int u = 0; u < 4; ++u) acc[c][u] += wv * E[m + u];
        }
      }
#pragma unroll
      for (int m = 0; m < 7; ++m) {        // odd kw = 2m+1
#pragma unroll
        for (int c = 0; c < 8; ++c) {
          float wv = wk[c * 675 + 2 * m + 1];
#pragma unroll
          for (int u = 0; u < 4; ++u) acc[c][u] += wv * O[m + u];
        }
      }
    }
  }
  if (valid) {
    float* dst = h1 + ((size_t)(b * 16 + cob) * 11 + d) * 20736 + y * 144 + x0;
#pragma unroll
    for (int c = 0; c < 8; ++c) {
      float bv = b1[cob + c];
      float4 o = {fmaxf(acc[c][0] + bv, 0.0f), fmaxf(acc[c][1] + bv, 0.0f),
                  fmaxf(acc[c][2] + bv, 0.0f), fmaxf(acc[c][3] + bv, 0.0f)};
      *(float4*)(dst + (size_t)c * 11 * 20736) = o;
    }
  }
}

// ---------------------------------------------------------------------------
// conv2 v4 (reverted, measured 810-826us): h1 -> 3 partials.
// linear LDS stride 76, immediate-offset b128, two barriers/stage, no
// held prefetch state. grid (18, 60) = 1080 blocks.
// ---------------------------------------------------------------------------
__global__ __launch_bounds__(256) void k_conv2(const float* __restrict__ h1,
                                               const float* __restrict__ w2t,
                                               float* __restrict__ h2p) {
  __shared__ alignas(16) float in_e[23 * 76];
  __shared__ alignas(16) float in_o[23 * 76];
  const int tid = threadIdx.x;
  const int wave = __builtin_amdgcn_readfirstlane(tid >> 6);
  const int lane = tid & 63;
  const int cob = wave * 8;
  const int bz = blockIdx.y;
  const int cig3 = bz % 3;
  const int t5 = bz / 3;
  const int b = t5 / 5, d = t5 % 5;
  const int g0 = blockIdx.x * 64;          // gi base (gi = r*17 + g)
  const int r0 = g0 / 17;
  const int row0 = 2 * r0;

  const int gi0 = g0 + lane;
  const bool valid = (gi0 < 1105);
  const int gi = valid ? gi0 : 1104;
  const int r = gi / 17;
  const int g = gi - r * 17;
  const int lr = r - r0;                   // 0..4
  const int x0 = g * 4;

  float acc[8][4] = {};

  for (int s = 0; s < 16; ++s) {
    const int u = cig3 * 16 + s;
    const int ci = u / 3;
    const int kd = u - 3 * ci;
    __syncthreads();
    const int din = 2 * d + kd;
    const float* src = h1 + (size_t)((b * 16 + ci) * 11 + din) * 20736;
    // stage 23 input rows x 144 cols, de-interleaved even/odd (stride 76)
    for (int i = tid; i < 23 * 36; i += 256) {
      int irr = i / 36, c4 = i - irr * 36;
      int gr = row0 + irr;
      float4 v = {0.0f, 0.0f, 0.0f, 0.0f};
      if (gr < 144) v = *(const float4*)(src + gr * 144 + c4 * 4);
      *(float2*)&in_e[irr * 76 + 2 * c4] = make_float2(v.x, v.z);
      *(float2*)&in_o[irr * 76 + 2 * c4] = make_float2(v.y, v.w);
    }
    __syncthreads();
    const float* wkb = w2t + (size_t)(ci * 3 + kd) * 225 * 32 + cob;  // uniform
    const float* pe0 = in_e + 2 * lr * 76 + x0;
    const float* po0 = in_o + 2 * lr * 76 + x0;
#pragma unroll 5
    for (int kh = 0; kh < 15; ++kh) {
      float4 e0 = *(const float4*)(pe0 + kh * 76);
      float4 e1 = *(const float4*)(pe0 + kh * 76 + 4);
      float4 e2 = *(const float4*)(pe0 + kh * 76 + 8);
      float4 o0 = *(const float4*)(po0 + kh * 76);
      float4 o1 = *(const float4*)(po0 + kh * 76 + 4);
      float4 o2 = *(const float4*)(po0 + kh * 76 + 8);
      float E[12] = {e0.x, e0.y, e0.z, e0.w, e1.x, e1.y, e1.z, e1.w,
                     e2.x, e2.y, e2.z, e2.w};
      float O[12] = {o0.x, o0.y, o0.z, o0.w, o1.x, o1.y, o1.z, o1.w,
                     o2.x, o2.y, o2.z, o2.w};
      const float* wk = wkb + kh * 480;     // 15 taps * 32 co
#pragma unroll
      for (int m = 0; m < 8; ++m) {         // even kw = 2m
#pragma unroll
        for (int c = 0; c < 8; ++c) {
          float wv = wk[m * 64 + c];
#pragma unroll
          for (int u2 = 0; u2 < 4; ++u2) acc[c][u2] += wv * E[m + u2];
        }
      }
#pragma unroll
      for (int m = 0; m < 7; ++m) {         // odd kw = 2m+1
#pragma unroll
        for (int c = 0; c < 8; ++c) {
          float wv = wk[m * 64 + 32 + c];
#pragma unroll
          for (int u2 = 0; u2 < 4; ++u2) acc[c][u2] += wv * O[m + u2];
        }
      }
    }
  }
  if (valid) {
    float* dst = h2p + (size_t)cig3 * 2704000 +
                 ((size_t)(b * 32 + cob) * 5 + d) * 4225 + r * 65 + x0;
#pragma unroll
    for (int c = 0; c < 8; ++c) {
#pragma unroll
      for (int u = 0; u < 4; ++u) {
        if (x0 + u < 65) dst[(size_t)c * 21125 + u] = acc[c][u];
      }
    }
  }
}

// combine conv2 partials (3) + bias + relu
__global__ __launch_bounds__(256) void k_h2fix(const float* __restrict__ p,
                                               const float* __restrict__ b2,
                                               float* __restrict__ h2) {
  int i = blockIdx.x * 256 + threadIdx.x;
  if (i >= 2704000) return;
  int co = (i / 21125) & 31;               // 21125 = 5*65*65
  float v = p[i] + p[2704000 + i] + p[5408000 + i] + b2[co];
  h2[i] = fmaxf(v, 0.0f);
}

// ---------------------------------------------------------------------------
// conv3: h2(4,32,5,65,65), w3t[ci][kd][k][16] -> 32 ci-partials
// Flattened-s: plane 26*26=676 per (b,d). grid (2 stile of 512, 8 planes, 32 ci).
// 4 waves = 2 co-groups(8co) x 2 s-groups(256 s). 512 blocks (2/CU).
// ---------------------------------------------------------------------------
__global__ __launch_bounds__(256) void k_conv3(const float* __restrict__ h2,
                                               const float* __restrict__ w3t,
                                               float* __restrict__ h3p) {
  __shared__ alignas(16) float in_e[55 * 36];
  __shared__ alignas(16) float in_o[55 * 36];
  const int tid = threadIdx.x;
  const int wave = __builtin_amdgcn_readfirstlane(tid >> 6);
  const int lane = tid & 63;
  const int cog = wave >> 1, sg = wave & 1;
  const int cob = cog * 8;
  const int bz = blockIdx.y;               // b*2 + d
  const int b = bz >> 1, d = bz & 1;
  const int ci = blockIdx.z;               // 0..31
  const int s0 = blockIdx.x * 512;
  const int y0 = s0 / 26;

  int sq[4], be[4];
  bool vq[4];
#pragma unroll
  for (int q = 0; q < 4; ++q) {
    int s = s0 + sg * 256 + q * 64 + lane;
    vq[q] = (s < 676);
    int sc = vq[q] ? s : 675;
    int y = sc / 26, xx = sc - y * 26;
    sq[q] = s;
    be[q] = 2 * (y - y0) * 36 + xx;
  }

  float acc[8][4] = {};

  for (int kd = 0; kd < 3; ++kd) {
    __syncthreads();
    const int din = 2 * d + kd;
    const float* src = h2 + (size_t)((b * 32 + ci) * 5 + din) * 4225;
    for (int i = tid; i < 55 * 65; i += 256) {
      int r = i / 65, c = i - r * 65;
      int gr = 2 * y0 + r;
      float v = (gr < 65) ? src[gr * 65 + c] : 0.0f;
      ((c & 1) ? in_o : in_e)[r * 36 + (c >> 1)] = v;
    }
    __syncthreads();
    const float* wkbase = w3t + (size_t)(ci * 3 + kd) * 225 * 16 + cob;  // uniform
    for (int kh = 0; kh < 15; ++kh) {
      float e[4][8], o[4][7];
#pragma unroll
      for (int q = 0; q < 4; ++q) {
        const float* pe = in_e + be[q] + kh * 36;
        const float* po = in_o + be[q] + kh * 36;
#pragma unroll
        for (int j = 0; j < 8; ++j) e[q][j] = pe[j];
#pragma unroll
        for (int j = 0; j < 7; ++j) o[q][j] = po[j];
      }
      const float* wr = wkbase + kh * 15 * 16;
#pragma unroll
      for (int j = 0; j < 8; ++j) {
#pragma unroll
        for (int c = 0; c < 8; ++c) {
          float wv = wr[(2 * j) * 16 + c];
#pragma unroll
          for (int q = 0; q < 4; ++q) acc[c][q] += wv * e[q][j];
        }
      }
#pragma unroll
      for (int j = 0; j < 7; ++j) {
#pragma unroll
        for (int c = 0; c < 8; ++c) {
          float wv = wr[(2 * j + 1) * 16 + c];
#pragma unroll
          for (int q = 0; q < 4; ++q) acc[c][q] += wv * o[q][j];
        }
      }
    }
  }
#pragma unroll
  for (int q = 0; q < 4; ++q) {
    if (vq[q]) {
#pragma unroll
      for (int c = 0; c < 8; ++c) {
        h3p[(size_t)ci * 86528 +
            ((size_t)(b * 16 + cob + c) * 2 + d) * 676 + sq[q]] = acc[c][q];
      }
    }
  }
}

// fold 32 conv3 partials + bias + relu -> prob = 0.5*x
__global__ __launch_bounds__(256) void k_h3fix(const float* __restrict__ h3p,
                                               const float* __restrict__ b3,
                                               float* __restrict__ prob) {
  int p = blockIdx.x * 256 + threadIdx.x;
  if (p >= 86528) return;
  int co = (p % 21632) / 1352;             // 1352 = 2*26*26
  float x = b3[co];
  for (int g = 0; g < 32; ++g) x += h3p[(size_t)g * 86528 + p];
  prob[p] = 0.5f * fmaxf(x, 0.0f);
}

// ---------------------------------------------------------------------------
// spikes: r = threefry-uniform; spk = (prob > r)
// grid (338, 30) block 256
// ---------------------------------------------------------------------------
__global__ __launch_bounds__(256) void k_spike(const float* __restrict__ prob,
                                               float* __restrict__ spk,
                                               SnnKeys keys) {
  int p = blockIdx.x * 256 + threadIdx.x;   // < 86528
  int t = blockIdx.y;
  float pr = prob[p];
  unsigned int x0 = 0u, x1 = (unsigned int)p;
  tf2x32(keys.k0[t], keys.k1[t], x0, x1);
  unsigned int bits = x0 ^ x1;              // partitionable 32-bit path
  float r = __uint_as_float((bits >> 9) | 0x3f800000u) - 1.0f;
  spk[(size_t)t * 86528 + p] = (pr > r) ? 1.0f : 0.0f;
}

// ---------------------------------------------------------------------------
// fc1 GEMM: inc_part[kc][m=(t*4+b)][n] = sum_k spk[m][k]*fc1_w[n][k]  (K split 26x832)
// grid (16 nt, 26 kc), block (8,16)=128. thread tile 8m x 4n.
// ---------------------------------------------------------------------------
__global__ __launch_bounds__(128) void k_fc1(const float* __restrict__ spk,
                                             const float* __restrict__ fc1w,
                                             float* __restrict__ incp) {
  __shared__ alignas(16) float slds[16][128];
  __shared__ alignas(16) float wlds[16][32];
  const int tx = threadIdx.x;               // 0..7
  const int ty = threadIdx.y;               // 0..15
  const int tid = ty * 8 + tx;
  const int nt = blockIdx.x;                // 0..15
  const int kc = blockIdx.y;                // 0..25
  const int k0base = kc * 832;

  float acc[8][4];
#pragma unroll
  for (int mi = 0; mi < 8; ++mi)
#pragma unroll
    for (int ni = 0; ni < 4; ++ni) acc[mi][ni] = 0.0f;

  for (int kb = 0; kb < 832; kb += 16) {
    const int k0 = k0base + kb;
    __syncthreads();
    {
      int m = tid;  // 0..127
      float4 v[4] = {{0,0,0,0},{0,0,0,0},{0,0,0,0},{0,0,0,0}};
      if (m < 120) {
        const float4* s = (const float4*)(spk + (size_t)m * 21632 + k0);
        v[0] = s[0]; v[1] = s[1]; v[2] = s[2]; v[3] = s[3];
      }
#pragma unroll
      for (int q = 0; q < 4; ++q) {
        slds[4 * q + 0][m] = v[q].x;
        slds[4 * q + 1][m] = v[q].y;
        slds[4 * q + 2][m] = v[q].z;
        slds[4 * q + 3][m] = v[q].w;
      }
    }
    for (int e = tid; e < 512; e += 128) {
      int n = e >> 4, kk = e & 15;
      wlds[kk][n] = fc1w[(size_t)(nt * 32 + n) * 21632 + k0 + kk];
    }
    __syncthreads();
#pragma unroll
    for (int kk = 0; kk < 16; ++kk) {
      const float4 wv = *(const float4*)&wlds[kk][tx * 4];
      const float4 s0 = *(const float4*)&slds[kk][ty * 8];
      const float4 s1 = *(const float4*)&slds[kk][ty * 8 + 4];
      float sv[8] = {s0.x, s0.y, s0.z, s0.w, s1.x, s1.y, s1.z, s1.w};
      float wz[4] = {wv.x, wv.y, wv.z, wv.w};
#pragma unroll
      for (int mi = 0; mi < 8; ++mi)
#pragma unroll
        for (int ni = 0; ni < 4; ++ni) acc[mi][ni] += sv[mi] * wz[ni];
    }
  }
#pragma unroll
  for (int mi = 0; mi < 8; ++mi) {
    int m = ty * 8 + mi;
    if (m < 120) {
      float4 o = {acc[mi][0], acc[mi][1], acc[mi][2], acc[mi][3]};
      *(float4*)&incp[((size_t)kc * 120 + m) * 512 + nt * 32 + tx * 4] = o;
    }
  }
}

// ---------------------------------------------------------------------------
// sequential membrane scan per (b,n): fire/reset, emit spike counts
// ---------------------------------------------------------------------------
__global__ __launch_bounds__(256) void k_scan(const float* __restrict__ incp,
                                              const float* __restrict__ fc1b,
                                              float* __restrict__ cnt) {
  int i = blockIdx.x * 256 + threadIdx.x;   // 0..2047
  int b = i >> 9, n = i & 511;
  float bias = fc1b[n];
  float m0 = 0.0f, c = 0.0f;
  for (int t = 0; t < 30; ++t) {
    int m = t * 4 + b;
    float s = bias;
    for (int kc = 0; kc < 26; ++kc) s += incp[((size_t)kc * 120 + m) * 512 + n];
    m0 += s;
    if (m0 > 1.0f) { c += 1.0f; m0 = 0.0f; }
  }
  cnt[i] = c;
}

// ---------------------------------------------------------------------------
// m1[b][o] = 30*fc2_b[o] + sum_n cnt[b][n]*fc2_w[o][n]
// ---------------------------------------------------------------------------
__global__ __launch_bounds__(256) void k_final(const float* __restrict__ cnt,
                                               const float* __restrict__ fc2w,
                                               const float* __restrict__ fc2b,
                                               float* __restrict__ out) {
  int o = threadIdx.x;
  if (o >= 216) return;
  int b = o / 54, oo = o - b * 54;
  const float* w = fc2w + (size_t)oo * 512;
  const float* c = cnt + (size_t)b * 512;
  float s = 0.0f;
  for (int n = 0; n < 512; ++n) s += c[n] * w[n];
  out[o] = s + 30.0f * fc2b[oo];
}

// ---------------------------------------------------------------------------
extern "C" void kernel_launch(void* const* d_in, const int* in_sizes, int n_in,
                              void* d_out, int out_size, void* d_ws, size_t ws_size,
                              hipStream_t stream) {
  (void)in_sizes; (void)n_in; (void)out_size; (void)ws_size;
  const float* x    = (const float*)d_in[0];
  const float* w1   = (const float*)d_in[1];
  const float* b1   = (const float*)d_in[2];
  const float* w2   = (const float*)d_in[3];
  const float* b2   = (const float*)d_in[4];
  const float* w3   = (const float*)d_in[5];
  const float* b3   = (const float*)d_in[6];
  const float* fc1w = (const float*)d_in[7];
  const float* fc1b = (const float*)d_in[8];
  const float* fc2w = (const float*)d_in[9];
  const float* fc2b = (const float*)d_in[10];
  float* out = (float*)d_out;
  float* ws  = (float*)d_ws;

  // workspace layout (floats); peak = xp+h1 = 23,295,840 fl = 93.2 MB (unchanged)
  float* xp   = ws;                       // [0 .. 8,697,696)            dead after conv1
  float* h1   = ws + 8697696;             // [8,697,696 .. 23,295,840)   dead after conv2
  float* w2t  = ws + 8112000;             // 345,600 in dead-xp tail [8,112,000..8,457,600)
  float* h2p  = ws;                       // 3 x 2,704,000 = [0 .. 8,112,000)
  float* h2   = ws + 8697696;             // [8,697,696 .. 11,401,696)  (dead h1 region)
  float* w3t  = ws;                       // 345,600 (in dead h2p; written after h2fix)
  float* h3p  = ws + 11401696;            // 32 x 86,528 = [11,401,696 .. 14,170,592)
  float* prob = ws + 14170592;            // 86,528 -> 14,257,120
  float* spk  = ws + 14257120;            // 2,595,840 -> 16,852,960
  float* incp = ws + 16852960;            // 26 x 61,440 -> 18,450,400
  float* cnt  = ws + 18450400;            // 2,048 (end 18,452,448 < 23,295,840)

  // host-side threefry: seed 42 -> key (0,42); partitionable split
  SnnKeys keys;
  for (int t = 0; t < 30; ++t) {
    unsigned int a = 0u, bb = (unsigned int)t;
    tf2x32(0u, 42u, a, bb);
    keys.k0[t] = a; keys.k1[t] = bb;
  }

  k_pool <<<(POOL_N + 255) / 256, 256, 0, stream>>>(x, xp);
  k_conv1<<<dim3(41, 44),    256, 0, stream>>>(xp, w1, b1, h1);
  k_wt2  <<<1350, 256, 0, stream>>>(w2, w2t);
  k_conv2<<<dim3(18, 60),    256, 0, stream>>>(h1, w2t, h2p);
  k_h2fix<<<(2704000 + 255) / 256, 256, 0, stream>>>(h2p, b2, h2);
  k_wt3  <<<1350, 256, 0, stream>>>(w3, w3t);
  k_conv3<<<dim3(2, 8, 32),  256, 0, stream>>>(h2, w3t, h3p);
  k_h3fix<<<338, 256, 0, stream>>>(h3p, b3, prob);
  k_spike<<<dim3(338, 30),   256, 0, stream>>>(prob, spk, keys);
  k_fc1  <<<dim3(16, 26), dim3(8, 16), 0, stream>>>(spk, fc1w, incp);
  k_scan <<<8, 256, 0, stream>>>(incp, fc1b, cnt);
  k_final<<<1, 256, 0, stream>>>(cnt, fc2w, fc2b, out);
}

// Round 12
// 1819.448 us; speedup vs baseline: 1.0981x; 1.0109x over previous
//
#include <hip/hip_runtime.h>
#include <stdint.h>

// ---------------------------------------------------------------------------
// JAX threefry2x32 (20 rounds), matching jax/_src/prng.py
// ---------------------------------------------------------------------------
struct SnnKeys { unsigned int k0[30]; unsigned int k1[30]; };

__host__ __device__ static inline void tf2x32(unsigned int k0, unsigned int k1,
                                              unsigned int& x0, unsigned int& x1) {
  unsigned int ks2 = k0 ^ k1 ^ 0x1BD11BDAu;
#define TF_RND(r) { x0 += x1; x1 = (x1 << (r)) | (x1 >> (32 - (r))); x1 ^= x0; }
  x0 += k0; x1 += k1;
  TF_RND(13) TF_RND(15) TF_RND(26) TF_RND(6)
  x0 += k1; x1 += ks2 + 1u;
  TF_RND(17) TF_RND(29) TF_RND(16) TF_RND(24)
  x0 += ks2; x1 += k0 + 2u;
  TF_RND(13) TF_RND(15) TF_RND(26) TF_RND(6)
  x0 += k0; x1 += k1 + 3u;
  TF_RND(17) TF_RND(29) TF_RND(16) TF_RND(24)
  x0 += k1; x1 += ks2 + 4u;
  TF_RND(13) TF_RND(15) TF_RND(26) TF_RND(6)
  x0 += ks2; x1 += k0 + 5u;
#undef TF_RND
}

// ---------------------------------------------------------------------------
// Stage 0: 2x2 average pool  x(4,24,602,602) -> xp(4,24,301,301)
// ---------------------------------------------------------------------------
#define POOL_N (4 * 24 * 301 * 301)

__global__ __launch_bounds__(256) void k_pool(const float* __restrict__ x,
                                              float* __restrict__ xp) {
  int i = blockIdx.x * 256 + threadIdx.x;
  if (i >= POOL_N) return;
  int j = i % 301;
  int rest = i / 301;
  int r = rest % 301;
  int bc = rest / 301;
  const float* src = x + ((size_t)bc * 602 + 2 * r) * 602 + 2 * j;
  float2 a = *(const float2*)src;
  float2 b = *(const float2*)(src + 602);
  xp[i] = 0.25f * ((a.x + a.y) + (b.x + b.y));
}

// ---------------------------------------------------------------------------
// weight transposes: [co][ci][kd][kh][kw] -> [ci][kd][kh][kw][co]
// ---------------------------------------------------------------------------
__global__ __launch_bounds__(256) void k_wt2(const float* __restrict__ w2,
                                             float* __restrict__ w2t) {
  int i = blockIdx.x * 256 + threadIdx.x;
  if (i >= 345600) return;
  int co = i & 31;
  int rest = i >> 5;            // ci*675 + kd*225 + k
  int ci = rest / 675;
  int k675 = rest - ci * 675;
  w2t[i] = w2[((size_t)co * 16 + ci) * 675 + k675];
}

__global__ __launch_bounds__(256) void k_wt3(const float* __restrict__ w3,
                                             float* __restrict__ w3t) {
  int i = blockIdx.x * 256 + threadIdx.x;
  if (i >= 345600) return;
  int co = i & 15;
  int rest = i >> 4;            // ci*675 + kd*225 + k
  int ci = rest / 675;
  int k675 = rest - ci * 675;
  w3t[i] = w3[((size_t)co * 32 + ci) * 675 + k675];
}

// ---------------------------------------------------------------------------
// conv1 v5: xp(4,[1],24,301,301), w1(16,1,3,15,15), s2 -> h1(4,16,11,144,144)
// v4 structure with LDS ROW STRIDE 156 (was 152): 2-row bank phase
// 312*lr % 32 = {0,24,16,8,0} — conv2's proven conflict pattern (v4's 152
// gave {0,16,0,16,0} = 3-way row-group collision; v3's 160 gave all-0).
// half-rows h in {0,1}, gi = y*36 + h*18 + g, x0 = h*72 + 4g; b128 reads.
// grid (41, 44). 4 waves = 2 co-groups(8co) x 2 gi-groups(64).
// ---------------------------------------------------------------------------
__global__ __launch_bounds__(256) void k_conv1(const float* __restrict__ xp,
                                               const float* __restrict__ w1,
                                               const float* __restrict__ b1,
                                               float* __restrict__ h1) {
  __shared__ alignas(16) float in_e[23 * 156];
  __shared__ alignas(16) float in_o[23 * 156];
  const int tid = threadIdx.x;
  const int wave = __builtin_amdgcn_readfirstlane(tid >> 6);
  const int lane = tid & 63;
  const int cog = wave >> 1, sg = wave & 1;
  const int cob = cog * 8;
  const int bz = blockIdx.y;
  const int b = bz / 11, d = bz % 11;
  const int g0 = blockIdx.x * 128;         // 128 gi per block (2 sg halves)
  const int y0 = g0 / 36;
  const int row0 = 2 * y0;

  const int gi0 = g0 + sg * 64 + lane;
  const bool valid = (gi0 < 5184);
  const int gi = valid ? gi0 : 5183;
  const int y = gi / 36;
  const int rem = gi - y * 36;
  const int h = rem / 18;
  const int g = rem - h * 18;
  const int lr = y - y0;                   // 0..4
  const int x0 = h * 72 + g * 4;           // 4-aligned -> b128-aligned reads

  float acc[8][4] = {};

  for (int kd = 0; kd < 3; ++kd) {
    __syncthreads();
    const int din = 2 * d + kd;
    const float* src = xp + (size_t)(b * 24 + din) * 90601;
    for (int i = tid; i < 23 * 301; i += 256) {
      int irr = i / 301, c = i - irr * 301;
      int gr = row0 + irr;
      float v = (gr < 301) ? src[gr * 301 + c] : 0.0f;
      ((c & 1) ? in_o : in_e)[irr * 156 + (c >> 1)] = v;
    }
    __syncthreads();
    const float* wp = w1 + cob * 675 + kd * 225;   // uniform (SGPR loads)
    const float* pe0 = in_e + 2 * lr * 156 + x0;
    const float* po0 = in_o + 2 * lr * 156 + x0;
#pragma unroll 5
    for (int kh = 0; kh < 15; ++kh) {
      float4 e0 = *(const float4*)(pe0 + kh * 156);
      float4 e1 = *(const float4*)(pe0 + kh * 156 + 4);
      float4 e2 = *(const float4*)(pe0 + kh * 156 + 8);
      float4 o0 = *(const float4*)(po0 + kh * 156);
      float4 o1 = *(const float4*)(po0 + kh * 156 + 4);
      float4 o2 = *(const float4*)(po0 + kh * 156 + 8);
      float E[12] = {e0.x, e0.y, e0.z, e0.w, e1.x, e1.y, e1.z, e1.w,
                     e2.x, e2.y, e2.z, e2.w};
      float O[12] = {o0.x, o0.y, o0.z, o0.w, o1.x, o1.y, o1.z, o1.w,
                     o2.x, o2.y, o2.z, o2.w};
      const float* wk = wp + kh * 15;
#pragma unroll
      for (int m = 0; m < 8; ++m) {        // even kw = 2m
#pragma unroll
        for (int c = 0; c < 8; ++c) {
          float wv = wk[c * 675 + 2 * m];
#pragma unroll
          for (int u = 0; u < 4; ++u) acc[c][u] += wv * E[m + u];
        }
      }
#pragma unroll
      for (int m = 0; m < 7; ++m) {        // odd kw = 2m+1
#pragma unroll
        for (int c = 0; c < 8; ++c) {
          float wv = wk[c * 675 + 2 * m + 1];
#pragma unroll
          for (int u = 0; u < 4; ++u) acc[c][u] += wv * O[m + u];
        }
      }
    }
  }
  if (valid) {
    float* dst = h1 + ((size_t)(b * 16 + cob) * 11 + d) * 20736 + y * 144 + x0;
#pragma unroll
    for (int c = 0; c < 8; ++c) {
      float bv = b1[cob + c];
      float4 o = {fmaxf(acc[c][0] + bv, 0.0f), fmaxf(acc[c][1] + bv, 0.0f),
                  fmaxf(acc[c][2] + bv, 0.0f), fmaxf(acc[c][3] + bv, 0.0f)};
      *(float4*)(dst + (size_t)c * 11 * 20736) = o;
    }
  }
}

// ---------------------------------------------------------------------------
// conv2 v4 (measured 810-826us): h1 -> 3 partials.
// linear LDS stride 76, immediate-offset b128, two barriers/stage, no
// held prefetch state. grid (18, 60) = 1080 blocks.
// ---------------------------------------------------------------------------
__global__ __launch_bounds__(256) void k_conv2(const float* __restrict__ h1,
                                               const float* __restrict__ w2t,
                                               float* __restrict__ h2p) {
  __shared__ alignas(16) float in_e[23 * 76];
  __shared__ alignas(16) float in_o[23 * 76];
  const int tid = threadIdx.x;
  const int wave = __builtin_amdgcn_readfirstlane(tid >> 6);
  const int lane = tid & 63;
  const int cob = wave * 8;
  const int bz = blockIdx.y;
  const int cig3 = bz % 3;
  const int t5 = bz / 3;
  const int b = t5 / 5, d = t5 % 5;
  const int g0 = blockIdx.x * 64;          // gi base (gi = r*17 + g)
  const int r0 = g0 / 17;
  const int row0 = 2 * r0;

  const int gi0 = g0 + lane;
  const bool valid = (gi0 < 1105);
  const int gi = valid ? gi0 : 1104;
  const int r = gi / 17;
  const int g = gi - r * 17;
  const int lr = r - r0;                   // 0..4
  const int x0 = g * 4;

  float acc[8][4] = {};

  for (int s = 0; s < 16; ++s) {
    const int u = cig3 * 16 + s;
    const int ci = u / 3;
    const int kd = u - 3 * ci;
    __syncthreads();
    const int din = 2 * d + kd;
    const float* src = h1 + (size_t)((b * 16 + ci) * 11 + din) * 20736;
    // stage 23 input rows x 144 cols, de-interleaved even/odd (stride 76)
    for (int i = tid; i < 23 * 36; i += 256) {
      int irr = i / 36, c4 = i - irr * 36;
      int gr = row0 + irr;
      float4 v = {0.0f, 0.0f, 0.0f, 0.0f};
      if (gr < 144) v = *(const float4*)(src + gr * 144 + c4 * 4);
      *(float2*)&in_e[irr * 76 + 2 * c4] = make_float2(v.x, v.z);
      *(float2*)&in_o[irr * 76 + 2 * c4] = make_float2(v.y, v.w);
    }
    __syncthreads();
    const float* wkb = w2t + (size_t)(ci * 3 + kd) * 225 * 32 + cob;  // uniform
    const float* pe0 = in_e + 2 * lr * 76 + x0;
    const float* po0 = in_o + 2 * lr * 76 + x0;
#pragma unroll 5
    for (int kh = 0; kh < 15; ++kh) {
      float4 e0 = *(const float4*)(pe0 + kh * 76);
      float4 e1 = *(const float4*)(pe0 + kh * 76 + 4);
      float4 e2 = *(const float4*)(pe0 + kh * 76 + 8);
      float4 o0 = *(const float4*)(po0 + kh * 76);
      float4 o1 = *(const float4*)(po0 + kh * 76 + 4);
      float4 o2 = *(const float4*)(po0 + kh * 76 + 8);
      float E[12] = {e0.x, e0.y, e0.z, e0.w, e1.x, e1.y, e1.z, e1.w,
                     e2.x, e2.y, e2.z, e2.w};
      float O[12] = {o0.x, o0.y, o0.z, o0.w, o1.x, o1.y, o1.z, o1.w,
                     o2.x, o2.y, o2.z, o2.w};
      const float* wk = wkb + kh * 480;     // 15 taps * 32 co
#pragma unroll
      for (int m = 0; m < 8; ++m) {         // even kw = 2m
#pragma unroll
        for (int c = 0; c < 8; ++c) {
          float wv = wk[m * 64 + c];
#pragma unroll
          for (int u2 = 0; u2 < 4; ++u2) acc[c][u2] += wv * E[m + u2];
        }
      }
#pragma unroll
      for (int m = 0; m < 7; ++m) {         // odd kw = 2m+1
#pragma unroll
        for (int c = 0; c < 8; ++c) {
          float wv = wk[m * 64 + 32 + c];
#pragma unroll
          for (int u2 = 0; u2 < 4; ++u2) acc[c][u2] += wv * O[m + u2];
        }
      }
    }
  }
  if (valid) {
    float* dst = h2p + (size_t)cig3 * 2704000 +
                 ((size_t)(b * 32 + cob) * 5 + d) * 4225 + r * 65 + x0;
#pragma unroll
    for (int c = 0; c < 8; ++c) {
#pragma unroll
      for (int u = 0; u < 4; ++u) {
        if (x0 + u < 65) dst[(size_t)c * 21125 + u] = acc[c][u];
      }
    }
  }
}

// combine conv2 partials (3) + bias + relu
__global__ __launch_bounds__(256) void k_h2fix(const float* __restrict__ p,
                                               const float* __restrict__ b2,
                                               float* __restrict__ h2) {
  int i = blockIdx.x * 256 + threadIdx.x;
  if (i >= 2704000) return;
  int co = (i / 21125) & 31;               // 21125 = 5*65*65
  float v = p[i] + p[2704000 + i] + p[5408000 + i] + b2[co];
  h2[i] = fmaxf(v, 0.0f);
}

// ---------------------------------------------------------------------------
// conv3: h2(4,32,5,65,65), w3t[ci][kd][k][16] -> 32 ci-partials
// Flattened-s: plane 26*26=676 per (b,d). grid (2 stile of 512, 8 planes, 32 ci).
// 4 waves = 2 co-groups(8co) x 2 s-groups(256 s). 512 blocks (2/CU).
// ---------------------------------------------------------------------------
__global__ __launch_bounds__(256) void k_conv3(const float* __restrict__ h2,
                                               const float* __restrict__ w3t,
                                               float* __restrict__ h3p) {
  __shared__ alignas(16) float in_e[55 * 36];
  __shared__ alignas(16) float in_o[55 * 36];
  const int tid = threadIdx.x;
  const int wave = __builtin_amdgcn_readfirstlane(tid >> 6);
  const int lane = tid & 63;
  const int cog = wave >> 1, sg = wave & 1;
  const int cob = cog * 8;
  const int bz = blockIdx.y;               // b*2 + d
  const int b = bz >> 1, d = bz & 1;
  const int ci = blockIdx.z;               // 0..31
  const int s0 = blockIdx.x * 512;
  const int y0 = s0 / 26;

  int sq[4], be[4];
  bool vq[4];
#pragma unroll
  for (int q = 0; q < 4; ++q) {
    int s = s0 + sg * 256 + q * 64 + lane;
    vq[q] = (s < 676);
    int sc = vq[q] ? s : 675;
    int y = sc / 26, xx = sc - y * 26;
    sq[q] = s;
    be[q] = 2 * (y - y0) * 36 + xx;
  }

  float acc[8][4] = {};

  for (int kd = 0; kd < 3; ++kd) {
    __syncthreads();
    const int din = 2 * d + kd;
    const float* src = h2 + (size_t)((b * 32 + ci) * 5 + din) * 4225;
    for (int i = tid; i < 55 * 65; i += 256) {
      int r = i / 65, c = i - r * 65;
      int gr = 2 * y0 + r;
      float v = (gr < 65) ? src[gr * 65 + c] : 0.0f;
      ((c & 1) ? in_o : in_e)[r * 36 + (c >> 1)] = v;
    }
    __syncthreads();
    const float* wkbase = w3t + (size_t)(ci * 3 + kd) * 225 * 16 + cob;  // uniform
    for (int kh = 0; kh < 15; ++kh) {
      float e[4][8], o[4][7];
#pragma unroll
      for (int q = 0; q < 4; ++q) {
        const float* pe = in_e + be[q] + kh * 36;
        const float* po = in_o + be[q] + kh * 36;
#pragma unroll
        for (int j = 0; j < 8; ++j) e[q][j] = pe[j];
#pragma unroll
        for (int j = 0; j < 7; ++j) o[q][j] = po[j];
      }
      const float* wr = wkbase + kh * 15 * 16;
#pragma unroll
      for (int j = 0; j < 8; ++j) {
#pragma unroll
        for (int c = 0; c < 8; ++c) {
          float wv = wr[(2 * j) * 16 + c];
#pragma unroll
          for (int q = 0; q < 4; ++q) acc[c][q] += wv * e[q][j];
        }
      }
#pragma unroll
      for (int j = 0; j < 7; ++j) {
#pragma unroll
        for (int c = 0; c < 8; ++c) {
          float wv = wr[(2 * j + 1) * 16 + c];
#pragma unroll
          for (int q = 0; q < 4; ++q) acc[c][q] += wv * o[q][j];
        }
      }
    }
  }
#pragma unroll
  for (int q = 0; q < 4; ++q) {
    if (vq[q]) {
#pragma unroll
      for (int c = 0; c < 8; ++c) {
        h3p[(size_t)ci * 86528 +
            ((size_t)(b * 16 + cob + c) * 2 + d) * 676 + sq[q]] = acc[c][q];
      }
    }
  }
}

// fold 32 conv3 partials + bias + relu -> prob = 0.5*x
__global__ __launch_bounds__(256) void k_h3fix(const float* __restrict__ h3p,
                                               const float* __restrict__ b3,
                                               float* __restrict__ prob) {
  int p = blockIdx.x * 256 + threadIdx.x;
  if (p >= 86528) return;
  int co = (p % 21632) / 1352;             // 1352 = 2*26*26
  float x = b3[co];
  for (int g = 0; g < 32; ++g) x += h3p[(size_t)g * 86528 + p];
  prob[p] = 0.5f * fmaxf(x, 0.0f);
}

// ---------------------------------------------------------------------------
// spikes: r = threefry-uniform; spk = (prob > r)
// grid (338, 30) block 256
// ---------------------------------------------------------------------------
__global__ __launch_bounds__(256) void k_spike(const float* __restrict__ prob,
                                               float* __restrict__ spk,
                                               SnnKeys keys) {
  int p = blockIdx.x * 256 + threadIdx.x;   // < 86528
  int t = blockIdx.y;
  float pr = prob[p];
  unsigned int x0 = 0u, x1 = (unsigned int)p;
  tf2x32(keys.k0[t], keys.k1[t], x0, x1);
  unsigned int bits = x0 ^ x1;              // partitionable 32-bit path
  float r = __uint_as_float((bits >> 9) | 0x3f800000u) - 1.0f;
  spk[(size_t)t * 86528 + p] = (pr > r) ? 1.0f : 0.0f;
}

// ---------------------------------------------------------------------------
// fc1 GEMM: inc_part[kc][m=(t*4+b)][n] = sum_k spk[m][k]*fc1_w[n][k]  (K split 26x832)
// grid (16 nt, 26 kc), block (8,16)=128. thread tile 8m x 4n.
// ---------------------------------------------------------------------------
__global__ __launch_bounds__(128) void k_fc1(const float* __restrict__ spk,
                                             const float* __restrict__ fc1w,
                                             float* __restrict__ incp) {
  __shared__ alignas(16) float slds[16][128];
  __shared__ alignas(16) float wlds[16][32];
  const int tx = threadIdx.x;               // 0..7
  const int ty = threadIdx.y;               // 0..15
  const int tid = ty * 8 + tx;
  const int nt = blockIdx.x;                // 0..15
  const int kc = blockIdx.y;                // 0..25
  const int k0base = kc * 832;

  float acc[8][4];
#pragma unroll
  for (int mi = 0; mi < 8; ++mi)
#pragma unroll
    for (int ni = 0; ni < 4; ++ni) acc[mi][ni] = 0.0f;

  for (int kb = 0; kb < 832; kb += 16) {
    const int k0 = k0base + kb;
    __syncthreads();
    {
      int m = tid;  // 0..127
      float4 v[4] = {{0,0,0,0},{0,0,0,0},{0,0,0,0},{0,0,0,0}};
      if (m < 120) {
        const float4* s = (const float4*)(spk + (size_t)m * 21632 + k0);
        v[0] = s[0]; v[1] = s[1]; v[2] = s[2]; v[3] = s[3];
      }
#pragma unroll
      for (int q = 0; q < 4; ++q) {
        slds[4 * q + 0][m] = v[q].x;
        slds[4 * q + 1][m] = v[q].y;
        slds[4 * q + 2][m] = v[q].z;
        slds[4 * q + 3][m] = v[q].w;
      }
    }
    for (int e = tid; e < 512; e += 128) {
      int n = e >> 4, kk = e & 15;
      wlds[kk][n] = fc1w[(size_t)(nt * 32 + n) * 21632 + k0 + kk];
    }
    __syncthreads();
#pragma unroll
    for (int kk = 0; kk < 16; ++kk) {
      const float4 wv = *(const float4*)&wlds[kk][tx * 4];
      const float4 s0 = *(const float4*)&slds[kk][ty * 8];
      const float4 s1 = *(const float4*)&slds[kk][ty * 8 + 4];
      float sv[8] = {s0.x, s0.y, s0.z, s0.w, s1.x, s1.y, s1.z, s1.w};
      float wz[4] = {wv.x, wv.y, wv.z, wv.w};
#pragma unroll
      for (int mi = 0; mi < 8; ++mi)
#pragma unroll
        for (int ni = 0; ni < 4; ++ni) acc[mi][ni] += sv[mi] * wz[ni];
    }
  }
#pragma unroll
  for (int mi = 0; mi < 8; ++mi) {
    int m = ty * 8 + mi;
    if (m < 120) {
      float4 o = {acc[mi][0], acc[mi][1], acc[mi][2], acc[mi][3]};
      *(float4*)&incp[((size_t)kc * 120 + m) * 512 + nt * 32 + tx * 4] = o;
    }
  }
}

// ---------------------------------------------------------------------------
// sequential membrane scan per (b,n): fire/reset, emit spike counts
// ---------------------------------------------------------------------------
__global__ __launch_bounds__(256) void k_scan(const float* __restrict__ incp,
                                              const float* __restrict__ fc1b,
                                              float* __restrict__ cnt) {
  int i = blockIdx.x * 256 + threadIdx.x;   // 0..2047
  int b = i >> 9, n = i & 511;
  float bias = fc1b[n];
  float m0 = 0.0f, c = 0.0f;
  for (int t = 0; t < 30; ++t) {
    int m = t * 4 + b;
    float s = bias;
    for (int kc = 0; kc < 26; ++kc) s += incp[((size_t)kc * 120 + m) * 512 + n];
    m0 += s;
    if (m0 > 1.0f) { c += 1.0f; m0 = 0.0f; }
  }
  cnt[i] = c;
}

// ---------------------------------------------------------------------------
// m1[b][o] = 30*fc2_b[o] + sum_n cnt[b][n]*fc2_w[o][n]
// ---------------------------------------------------------------------------
__global__ __launch_bounds__(256) void k_final(const float* __restrict__ cnt,
                                               const float* __restrict__ fc2w,
                                               const float* __restrict__ fc2b,
                                               float* __restrict__ out) {
  int o = threadIdx.x;
  if (o >= 216) return;
  int b = o / 54, oo = o - b * 54;
  const float* w = fc2w + (size_t)oo * 512;
  const float* c = cnt + (size_t)b * 512;
  float s = 0.0f;
  for (int n = 0; n < 512; ++n) s += c[n] * w[n];
  out[o] = s + 30.0f * fc2b[oo];
}

// ---------------------------------------------------------------------------
extern "C" void kernel_launch(void* const* d_in, const int* in_sizes, int n_in,
                              void* d_out, int out_size, void* d_ws, size_t ws_size,
                              hipStream_t stream) {
  (void)in_sizes; (void)n_in; (void)out_size; (void)ws_size;
  const float* x    = (const float*)d_in[0];
  const float* w1   = (const float*)d_in[1];
  const float* b1   = (const float*)d_in[2];
  const float* w2   = (const float*)d_in[3];
  const float* b2   = (const float*)d_in[4];
  const float* w3   = (const float*)d_in[5];
  const float* b3   = (const float*)d_in[6];
  const float* fc1w = (const float*)d_in[7];
  const float* fc1b = (const float*)d_in[8];
  const float* fc2w = (const float*)d_in[9];
  const float* fc2b = (const float*)d_in[10];
  float* out = (float*)d_out;
  float* ws  = (float*)d_ws;

  // workspace layout (floats); peak = xp+h1 = 23,295,840 fl = 93.2 MB (unchanged)
  float* xp   = ws;                       // [0 .. 8,697,696)            dead after conv1
  float* h1   = ws + 8697696;             // [8,697,696 .. 23,295,840)   dead after conv2
  float* w2t  = ws + 8112000;             // 345,600 in dead-xp tail [8,112,000..8,457,600)
  float* h2p  = ws;                       // 3 x 2,704,000 = [0 .. 8,112,000)
  float* h2   = ws + 8697696;             // [8,697,696 .. 11,401,696)  (dead h1 region)
  float* w3t  = ws;                       // 345,600 (in dead h2p; written after h2fix)
  float* h3p  = ws + 11401696;            // 32 x 86,528 = [11,401,696 .. 14,170,592)
  float* prob = ws + 14170592;            // 86,528 -> 14,257,120
  float* spk  = ws + 14257120;            // 2,595,840 -> 16,852,960
  float* incp = ws + 16852960;            // 26 x 61,440 -> 18,450,400
  float* cnt  = ws + 18450400;            // 2,048 (end 18,452,448 < 23,295,840)

  // host-side threefry: seed 42 -> key (0,42); partitionable split
  SnnKeys keys;
  for (int t = 0; t < 30; ++t) {
    unsigned int a = 0u, bb = (unsigned int)t;
    tf2x32(0u, 42u, a, bb);
    keys.k0[t] = a; keys.k1[t] = bb;
  }

  k_pool <<<(POOL_N + 255) / 256, 256, 0, stream>>>(x, xp);
  k_conv1<<<dim3(41, 44),    256, 0, stream>>>(xp, w1, b1, h1);
  k_wt2  <<<1350, 256, 0, stream>>>(w2, w2t);
  k_conv2<<<dim3(18, 60),    256, 0, stream>>>(h1, w2t, h2p);
  k_h2fix<<<(2704000 + 255) / 256, 256, 0, stream>>>(h2p, b2, h2);
  k_wt3  <<<1350, 256, 0, stream>>>(w3, w3t);
  k_conv3<<<dim3(2, 8, 32),  256, 0, stream>>>(h2, w3t, h3p);
  k_h3fix<<<338, 256, 0, stream>>>(h3p, b3, prob);
  k_spike<<<dim3(338, 30),   256, 0, stream>>>(prob, spk, keys);
  k_fc1  <<<dim3(16, 26), dim3(8, 16), 0, stream>>>(spk, fc1w, incp);
  k_scan <<<8, 256, 0, stream>>>(incp, fc1b, cnt);
  k_final<<<1, 256, 0, stream>>>(cnt, fc2w, fc2b, out);
}

// Round 13
// 1562.759 us; speedup vs baseline: 1.2785x; 1.1643x over previous
//
#include <hip/hip_runtime.h>
#include <stdint.h>

// ---------------------------------------------------------------------------
// JAX threefry2x32 (20 rounds), matching jax/_src/prng.py
// ---------------------------------------------------------------------------
struct SnnKeys { unsigned int k0[30]; unsigned int k1[30]; };

__host__ __device__ static inline void tf2x32(unsigned int k0, unsigned int k1,
                                              unsigned int& x0, unsigned int& x1) {
  unsigned int ks2 = k0 ^ k1 ^ 0x1BD11BDAu;
#define TF_RND(r) { x0 += x1; x1 = (x1 << (r)) | (x1 >> (32 - (r))); x1 ^= x0; }
  x0 += k0; x1 += k1;
  TF_RND(13) TF_RND(15) TF_RND(26) TF_RND(6)
  x0 += k1; x1 += ks2 + 1u;
  TF_RND(17) TF_RND(29) TF_RND(16) TF_RND(24)
  x0 += ks2; x1 += k0 + 2u;
  TF_RND(13) TF_RND(15) TF_RND(26) TF_RND(6)
  x0 += k0; x1 += k1 + 3u;
  TF_RND(17) TF_RND(29) TF_RND(16) TF_RND(24)
  x0 += k1; x1 += ks2 + 4u;
  TF_RND(13) TF_RND(15) TF_RND(26) TF_RND(6)
  x0 += ks2; x1 += k0 + 5u;
#undef TF_RND
}

// ---------------------------------------------------------------------------
// Stage 0: 2x2 average pool  x(4,24,602,602) -> xp(4,24,301,301)
// ---------------------------------------------------------------------------
#define POOL_N (4 * 24 * 301 * 301)

__global__ __launch_bounds__(256) void k_pool(const float* __restrict__ x,
                                              float* __restrict__ xp) {
  int i = blockIdx.x * 256 + threadIdx.x;
  if (i >= POOL_N) return;
  int j = i % 301;
  int rest = i / 301;
  int r = rest % 301;
  int bc = rest / 301;
  const float* src = x + ((size_t)bc * 602 + 2 * r) * 602 + 2 * j;
  float2 a = *(const float2*)src;
  float2 b = *(const float2*)(src + 602);
  xp[i] = 0.25f * ((a.x + a.y) + (b.x + b.y));
}

// ---------------------------------------------------------------------------
// weight transposes: [co][ci][kd][kh][kw] -> [ci][kd][kh][kw][co]
// ---------------------------------------------------------------------------
__global__ __launch_bounds__(256) void k_wt2(const float* __restrict__ w2,
                                             float* __restrict__ w2t) {
  int i = blockIdx.x * 256 + threadIdx.x;
  if (i >= 345600) return;
  int co = i & 31;
  int rest = i >> 5;            // ci*675 + kd*225 + k
  int ci = rest / 675;
  int k675 = rest - ci * 675;
  w2t[i] = w2[((size_t)co * 16 + ci) * 675 + k675];
}

__global__ __launch_bounds__(256) void k_wt3(const float* __restrict__ w3,
                                             float* __restrict__ w3t) {
  int i = blockIdx.x * 256 + threadIdx.x;
  if (i >= 345600) return;
  int co = i & 15;
  int rest = i >> 4;            // ci*675 + kd*225 + k
  int ci = rest / 675;
  int k675 = rest - ci * 675;
  w3t[i] = w3[((size_t)co * 32 + ci) * 675 + k675];
}

// ---------------------------------------------------------------------------
// conv1 (R1 original, PERMANENT): xp(4,[1],24,301,301), w1(16,1,3,15,15), s2
// -> h1(4,16,11,144,144), relu.  grid (41 stile of 512 s, 44 b*d).
// 4 waves = 2 co-groups(8co) x 2 s-groups(256 s). Consecutive-lane b32 LDS
// reads (conflict-free); b128 restructures regress +270us (R5/R11/R12).
// ---------------------------------------------------------------------------
__global__ __launch_bounds__(256) void k_conv1(const float* __restrict__ xp,
                                               const float* __restrict__ w1,
                                               const float* __restrict__ b1,
                                               float* __restrict__ h1) {
  __shared__ alignas(16) float in_e[25 * 152];
  __shared__ alignas(16) float in_o[25 * 152];
  const int tid = threadIdx.x;
  const int wave = __builtin_amdgcn_readfirstlane(tid >> 6);
  const int lane = tid & 63;
  const int cog = wave >> 1, sg = wave & 1;
  const int cob = cog * 8;
  const int bz = blockIdx.y;
  const int b = bz / 11, d = bz % 11;
  const int s0 = blockIdx.x * 512;
  const int y0 = s0 / 144;

  int sq[4], be[4];
  bool vq[4];
#pragma unroll
  for (int q = 0; q < 4; ++q) {
    int s = s0 + sg * 256 + q * 64 + lane;
    vq[q] = (s < 20736);
    int sc = vq[q] ? s : 20735;
    int y = sc / 144, xx = sc - y * 144;
    sq[q] = s;
    be[q] = 2 * (y - y0) * 152 + xx;
  }

  float acc[8][4] = {};

  for (int kd = 0; kd < 3; ++kd) {
    __syncthreads();
    const int din = 2 * d + kd;
    const float* src = xp + (size_t)(b * 24 + din) * 90601;
    for (int i = tid; i < 25 * 301; i += 256) {
      int r = i / 301, c = i - r * 301;
      int gr = 2 * y0 + r;
      float v = (gr < 301) ? src[gr * 301 + c] : 0.0f;
      ((c & 1) ? in_o : in_e)[r * 152 + (c >> 1)] = v;
    }
    __syncthreads();
    const float* wp = w1 + cob * 675 + kd * 225;   // wp[c*675 + kh*15 + kw], uniform
    for (int kh = 0; kh < 15; ++kh) {
      float e[4][8], o[4][7];
#pragma unroll
      for (int q = 0; q < 4; ++q) {
        const float* pe = in_e + be[q] + kh * 152;
        const float* po = in_o + be[q] + kh * 152;
#pragma unroll
        for (int j = 0; j < 8; ++j) e[q][j] = pe[j];
#pragma unroll
        for (int j = 0; j < 7; ++j) o[q][j] = po[j];
      }
      const float* wk = wp + kh * 15;
#pragma unroll
      for (int j = 0; j < 8; ++j) {
#pragma unroll
        for (int c = 0; c < 8; ++c) {
          float wv = wk[c * 675 + 2 * j];
#pragma unroll
          for (int q = 0; q < 4; ++q) acc[c][q] += wv * e[q][j];
        }
      }
#pragma unroll
      for (int j = 0; j < 7; ++j) {
#pragma unroll
        for (int c = 0; c < 8; ++c) {
          float wv = wk[c * 675 + 2 * j + 1];
#pragma unroll
          for (int q = 0; q < 4; ++q) acc[c][q] += wv * o[q][j];
        }
      }
    }
  }
#pragma unroll
  for (int q = 0; q < 4; ++q) {
    if (vq[q]) {
#pragma unroll
      for (int c = 0; c < 8; ++c) {
        float v = acc[c][q] + b1[cob + c];
        h1[((size_t)(b * 16 + cob + c) * 11 + d) * 20736 + sq[q]] = fmaxf(v, 0.0f);
      }
    }
  }
}

// ---------------------------------------------------------------------------
// conv2 v6: h1(4,16,11,144,144), w2t[ci][kd][k][32] -> 3 partials
// v4 compute structure + PAIRED STAGING: two (ci,kd) units staged into two
// LDS buffer sets per barrier pair (8 pairs, was 16) -> half the barrier
// drains, 8-deep load batch. No state held across compute (R10 lesson).
// grid (18, 60) = 1080 blocks.
// ---------------------------------------------------------------------------
__global__ __launch_bounds__(256) void k_conv2(const float* __restrict__ h1,
                                               const float* __restrict__ w2t,
                                               float* __restrict__ h2p) {
  __shared__ alignas(16) float in_e[2][23 * 76];
  __shared__ alignas(16) float in_o[2][23 * 76];
  const int tid = threadIdx.x;
  const int wave = __builtin_amdgcn_readfirstlane(tid >> 6);
  const int lane = tid & 63;
  const int cob = wave * 8;
  const int bz = blockIdx.y;
  const int cig3 = bz % 3;
  const int t5 = bz / 3;
  const int b = t5 / 5, d = t5 % 5;
  const int g0 = blockIdx.x * 64;          // gi base (gi = r*17 + g)
  const int r0 = g0 / 17;
  const int row0 = 2 * r0;

  const int gi0 = g0 + lane;
  const bool valid = (gi0 < 1105);
  const int gi = valid ? gi0 : 1104;
  const int r = gi / 17;
  const int g = gi - r * 17;
  const int lr = r - r0;                   // 0..4
  const int x0 = g * 4;

  float acc[8][4] = {};

  for (int sp = 0; sp < 8; ++sp) {
    __syncthreads();
#pragma unroll
    for (int half = 0; half < 2; ++half) {
      const int u = cig3 * 16 + sp * 2 + half;
      const int ci = u / 3;
      const int kd = u - 3 * ci;
      const int din = 2 * d + kd;
      const float* src = h1 + (size_t)((b * 16 + ci) * 11 + din) * 20736;
      for (int i = tid; i < 23 * 36; i += 256) {
        int irr = i / 36, c4 = i - irr * 36;
        int gr = row0 + irr;
        float4 v = {0.0f, 0.0f, 0.0f, 0.0f};
        if (gr < 144) v = *(const float4*)(src + gr * 144 + c4 * 4);
        *(float2*)&in_e[half][irr * 76 + 2 * c4] = make_float2(v.x, v.z);
        *(float2*)&in_o[half][irr * 76 + 2 * c4] = make_float2(v.y, v.w);
      }
    }
    __syncthreads();
#pragma unroll
    for (int half = 0; half < 2; ++half) {
      const int u = cig3 * 16 + sp * 2 + half;
      const int ci = u / 3;
      const int kd = u - 3 * ci;
      const float* wkb = w2t + (size_t)(ci * 3 + kd) * 225 * 32 + cob;  // uniform
      const float* pe0 = &in_e[half][2 * lr * 76 + x0];
      const float* po0 = &in_o[half][2 * lr * 76 + x0];
#pragma unroll 5
      for (int kh = 0; kh < 15; ++kh) {
        float4 e0 = *(const float4*)(pe0 + kh * 76);
        float4 e1 = *(const float4*)(pe0 + kh * 76 + 4);
        float4 e2 = *(const float4*)(pe0 + kh * 76 + 8);
        float4 o0 = *(const float4*)(po0 + kh * 76);
        float4 o1 = *(const float4*)(po0 + kh * 76 + 4);
        float4 o2 = *(const float4*)(po0 + kh * 76 + 8);
        float E[12] = {e0.x, e0.y, e0.z, e0.w, e1.x, e1.y, e1.z, e1.w,
                       e2.x, e2.y, e2.z, e2.w};
        float O[12] = {o0.x, o0.y, o0.z, o0.w, o1.x, o1.y, o1.z, o1.w,
                       o2.x, o2.y, o2.z, o2.w};
        const float* wk = wkb + kh * 480;   // 15 taps * 32 co
#pragma unroll
        for (int m = 0; m < 8; ++m) {       // even kw = 2m
#pragma unroll
          for (int c = 0; c < 8; ++c) {
            float wv = wk[m * 64 + c];
#pragma unroll
            for (int u2 = 0; u2 < 4; ++u2) acc[c][u2] += wv * E[m + u2];
          }
        }
#pragma unroll
        for (int m = 0; m < 7; ++m) {       // odd kw = 2m+1
#pragma unroll
          for (int c = 0; c < 8; ++c) {
            float wv = wk[m * 64 + 32 + c];
#pragma unroll
            for (int u2 = 0; u2 < 4; ++u2) acc[c][u2] += wv * O[m + u2];
          }
        }
      }
    }
  }
  if (valid) {
    float* dst = h2p + (size_t)cig3 * 2704000 +
                 ((size_t)(b * 32 + cob) * 5 + d) * 4225 + r * 65 + x0;
#pragma unroll
    for (int c = 0; c < 8; ++c) {
#pragma unroll
      for (int u = 0; u < 4; ++u) {
        if (x0 + u < 65) dst[(size_t)c * 21125 + u] = acc[c][u];
      }
    }
  }
}

// combine conv2 partials (3) + bias + relu
__global__ __launch_bounds__(256) void k_h2fix(const float* __restrict__ p,
                                               const float* __restrict__ b2,
                                               float* __restrict__ h2) {
  int i = blockIdx.x * 256 + threadIdx.x;
  if (i >= 2704000) return;
  int co = (i / 21125) & 31;               // 21125 = 5*65*65
  float v = p[i] + p[2704000 + i] + p[5408000 + i] + b2[co];
  h2[i] = fmaxf(v, 0.0f);
}

// ---------------------------------------------------------------------------
// conv3: h2(4,32,5,65,65), w3t[ci][kd][k][16] -> 32 ci-partials
// Flattened-s: plane 26*26=676 per (b,d). grid (2 stile of 512, 8 planes, 32 ci).
// 4 waves = 2 co-groups(8co) x 2 s-groups(256 s). 512 blocks (2/CU).
// ---------------------------------------------------------------------------
__global__ __launch_bounds__(256) void k_conv3(const float* __restrict__ h2,
                                               const float* __restrict__ w3t,
                                               float* __restrict__ h3p) {
  __shared__ alignas(16) float in_e[55 * 36];
  __shared__ alignas(16) float in_o[55 * 36];
  const int tid = threadIdx.x;
  const int wave = __builtin_amdgcn_readfirstlane(tid >> 6);
  const int lane = tid & 63;
  const int cog = wave >> 1, sg = wave & 1;
  const int cob = cog * 8;
  const int bz = blockIdx.y;               // b*2 + d
  const int b = bz >> 1, d = bz & 1;
  const int ci = blockIdx.z;               // 0..31
  const int s0 = blockIdx.x * 512;
  const int y0 = s0 / 26;

  int sq[4], be[4];
  bool vq[4];
#pragma unroll
  for (int q = 0; q < 4; ++q) {
    int s = s0 + sg * 256 + q * 64 + lane;
    vq[q] = (s < 676);
    int sc = vq[q] ? s : 675;
    int y = sc / 26, xx = sc - y * 26;
    sq[q] = s;
    be[q] = 2 * (y - y0) * 36 + xx;
  }

  float acc[8][4] = {};

  for (int kd = 0; kd < 3; ++kd) {
    __syncthreads();
    const int din = 2 * d + kd;
    const float* src = h2 + (size_t)((b * 32 + ci) * 5 + din) * 4225;
    for (int i = tid; i < 55 * 65; i += 256) {
      int r = i / 65, c = i - r * 65;
      int gr = 2 * y0 + r;
      float v = (gr < 65) ? src[gr * 65 + c] : 0.0f;
      ((c & 1) ? in_o : in_e)[r * 36 + (c >> 1)] = v;
    }
    __syncthreads();
    const float* wkbase = w3t + (size_t)(ci * 3 + kd) * 225 * 16 + cob;  // uniform
    for (int kh = 0; kh < 15; ++kh) {
      float e[4][8], o[4][7];
#pragma unroll
      for (int q = 0; q < 4; ++q) {
        const float* pe = in_e + be[q] + kh * 36;
        const float* po = in_o + be[q] + kh * 36;
#pragma unroll
        for (int j = 0; j < 8; ++j) e[q][j] = pe[j];
#pragma unroll
        for (int j = 0; j < 7; ++j) o[q][j] = po[j];
      }
      const float* wr = wkbase + kh * 15 * 16;
#pragma unroll
      for (int j = 0; j < 8; ++j) {
#pragma unroll
        for (int c = 0; c < 8; ++c) {
          float wv = wr[(2 * j) * 16 + c];
#pragma unroll
          for (int q = 0; q < 4; ++q) acc[c][q] += wv * e[q][j];
        }
      }
#pragma unroll
      for (int j = 0; j < 7; ++j) {
#pragma unroll
        for (int c = 0; c < 8; ++c) {
          float wv = wr[(2 * j + 1) * 16 + c];
#pragma unroll
          for (int q = 0; q < 4; ++q) acc[c][q] += wv * o[q][j];
        }
      }
    }
  }
#pragma unroll
  for (int q = 0; q < 4; ++q) {
    if (vq[q]) {
#pragma unroll
      for (int c = 0; c < 8; ++c) {
        h3p[(size_t)ci * 86528 +
            ((size_t)(b * 16 + cob + c) * 2 + d) * 676 + sq[q]] = acc[c][q];
      }
    }
  }
}

// fold 32 conv3 partials + bias + relu -> prob = 0.5*x
__global__ __launch_bounds__(256) void k_h3fix(const float* __restrict__ h3p,
                                               const float* __restrict__ b3,
                                               float* __restrict__ prob) {
  int p = blockIdx.x * 256 + threadIdx.x;
  if (p >= 86528) return;
  int co = (p % 21632) / 1352;             // 1352 = 2*26*26
  float x = b3[co];
  for (int g = 0; g < 32; ++g) x += h3p[(size_t)g * 86528 + p];
  prob[p] = 0.5f * fmaxf(x, 0.0f);
}

// ---------------------------------------------------------------------------
// spikes: r = threefry-uniform; spk = (prob > r)
// grid (338, 30) block 256
// ---------------------------------------------------------------------------
__global__ __launch_bounds__(256) void k_spike(const float* __restrict__ prob,
                                               float* __restrict__ spk,
                                               SnnKeys keys) {
  int p = blockIdx.x * 256 + threadIdx.x;   // < 86528
  int t = blockIdx.y;
  float pr = prob[p];
  unsigned int x0 = 0u, x1 = (unsigned int)p;
  tf2x32(keys.k0[t], keys.k1[t], x0, x1);
  unsigned int bits = x0 ^ x1;              // partitionable 32-bit path
  float r = __uint_as_float((bits >> 9) | 0x3f800000u) - 1.0f;
  spk[(size_t)t * 86528 + p] = (pr > r) ? 1.0f : 0.0f;
}

// ---------------------------------------------------------------------------
// fc1 GEMM: inc_part[kc][m=(t*4+b)][n] = sum_k spk[m][k]*fc1_w[n][k]  (K split 26x832)
// grid (16 nt, 26 kc), block (8,16)=128. thread tile 8m x 4n.
// ---------------------------------------------------------------------------
__global__ __launch_bounds__(128) void k_fc1(const float* __restrict__ spk,
                                             const float* __restrict__ fc1w,
                                             float* __restrict__ incp) {
  __shared__ alignas(16) float slds[16][128];
  __shared__ alignas(16) float wlds[16][32];
  const int tx = threadIdx.x;               // 0..7
  const int ty = threadIdx.y;               // 0..15
  const int tid = ty * 8 + tx;
  const int nt = blockIdx.x;                // 0..15
  const int kc = blockIdx.y;                // 0..25
  const int k0base = kc * 832;

  float acc[8][4];
#pragma unroll
  for (int mi = 0; mi < 8; ++mi)
#pragma unroll
    for (int ni = 0; ni < 4; ++ni) acc[mi][ni] = 0.0f;

  for (int kb = 0; kb < 832; kb += 16) {
    const int k0 = k0base + kb;
    __syncthreads();
    {
      int m = tid;  // 0..127
      float4 v[4] = {{0,0,0,0},{0,0,0,0},{0,0,0,0},{0,0,0,0}};
      if (m < 120) {
        const float4* s = (const float4*)(spk + (size_t)m * 21632 + k0);
        v[0] = s[0]; v[1] = s[1]; v[2] = s[2]; v[3] = s[3];
      }
#pragma unroll
      for (int q = 0; q < 4; ++q) {
        slds[4 * q + 0][m] = v[q].x;
        slds[4 * q + 1][m] = v[q].y;
        slds[4 * q + 2][m] = v[q].z;
        slds[4 * q + 3][m] = v[q].w;
      }
    }
    for (int e = tid; e < 512; e += 128) {
      int n = e >> 4, kk = e & 15;
      wlds[kk][n] = fc1w[(size_t)(nt * 32 + n) * 21632 + k0 + kk];
    }
    __syncthreads();
#pragma unroll
    for (int kk = 0; kk < 16; ++kk) {
      const float4 wv = *(const float4*)&wlds[kk][tx * 4];
      const float4 s0 = *(const float4*)&slds[kk][ty * 8];
      const float4 s1 = *(const float4*)&slds[kk][ty * 8 + 4];
      float sv[8] = {s0.x, s0.y, s0.z, s0.w, s1.x, s1.y, s1.z, s1.w};
      float wz[4] = {wv.x, wv.y, wv.z, wv.w};
#pragma unroll
      for (int mi = 0; mi < 8; ++mi)
#pragma unroll
        for (int ni = 0; ni < 4; ++ni) acc[mi][ni] += sv[mi] * wz[ni];
    }
  }
#pragma unroll
  for (int mi = 0; mi < 8; ++mi) {
    int m = ty * 8 + mi;
    if (m < 120) {
      float4 o = {acc[mi][0], acc[mi][1], acc[mi][2], acc[mi][3]};
      *(float4*)&incp[((size_t)kc * 120 + m) * 512 + nt * 32 + tx * 4] = o;
    }
  }
}

// ---------------------------------------------------------------------------
// sequential membrane scan per (b,n): fire/reset, emit spike counts
// ---------------------------------------------------------------------------
__global__ __launch_bounds__(256) void k_scan(const float* __restrict__ incp,
                                              const float* __restrict__ fc1b,
                                              float* __restrict__ cnt) {
  int i = blockIdx.x * 256 + threadIdx.x;   // 0..2047
  int b = i >> 9, n = i & 511;
  float bias = fc1b[n];
  float m0 = 0.0f, c = 0.0f;
  for (int t = 0; t < 30; ++t) {
    int m = t * 4 + b;
    float s = bias;
    for (int kc = 0; kc < 26; ++kc) s += incp[((size_t)kc * 120 + m) * 512 + n];
    m0 += s;
    if (m0 > 1.0f) { c += 1.0f; m0 = 0.0f; }
  }
  cnt[i] = c;
}

// ---------------------------------------------------------------------------
// m1[b][o] = 30*fc2_b[o] + sum_n cnt[b][n]*fc2_w[o][n]
// ---------------------------------------------------------------------------
__global__ __launch_bounds__(256) void k_final(const float* __restrict__ cnt,
                                               const float* __restrict__ fc2w,
                                               const float* __restrict__ fc2b,
                                               float* __restrict__ out) {
  int o = threadIdx.x;
  if (o >= 216) return;
  int b = o / 54, oo = o - b * 54;
  const float* w = fc2w + (size_t)oo * 512;
  const float* c = cnt + (size_t)b * 512;
  float s = 0.0f;
  for (int n = 0; n < 512; ++n) s += c[n] * w[n];
  out[o] = s + 30.0f * fc2b[oo];
}

// ---------------------------------------------------------------------------
extern "C" void kernel_launch(void* const* d_in, const int* in_sizes, int n_in,
                              void* d_out, int out_size, void* d_ws, size_t ws_size,
                              hipStream_t stream) {
  (void)in_sizes; (void)n_in; (void)out_size; (void)ws_size;
  const float* x    = (const float*)d_in[0];
  const float* w1   = (const float*)d_in[1];
  const float* b1   = (const float*)d_in[2];
  const float* w2   = (const float*)d_in[3];
  const float* b2   = (const float*)d_in[4];
  const float* w3   = (const float*)d_in[5];
  const float* b3   = (const float*)d_in[6];
  const float* fc1w = (const float*)d_in[7];
  const float* fc1b = (const float*)d_in[8];
  const float* fc2w = (const float*)d_in[9];
  const float* fc2b = (const float*)d_in[10];
  float* out = (float*)d_out;
  float* ws  = (float*)d_ws;

  // workspace layout (floats); peak = xp+h1 = 23,295,840 fl = 93.2 MB (unchanged)
  float* xp   = ws;                       // [0 .. 8,697,696)            dead after conv1
  float* h1   = ws + 8697696;             // [8,697,696 .. 23,295,840)   dead after conv2
  float* w2t  = ws + 8112000;             // 345,600 in dead-xp tail [8,112,000..8,457,600)
  float* h2p  = ws;                       // 3 x 2,704,000 = [0 .. 8,112,000)
  float* h2   = ws + 8697696;             // [8,697,696 .. 11,401,696)  (dead h1 region)
  float* w3t  = ws;                       // 345,600 (in dead h2p; written after h2fix)
  float* h3p  = ws + 11401696;            // 32 x 86,528 = [11,401,696 .. 14,170,592)
  float* prob = ws + 14170592;            // 86,528 -> 14,257,120
  float* spk  = ws + 14257120;            // 2,595,840 -> 16,852,960
  float* incp = ws + 16852960;            // 26 x 61,440 -> 18,450,400
  float* cnt  = ws + 18450400;            // 2,048 (end 18,452,448 < 23,295,840)

  // host-side threefry: seed 42 -> key (0,42); partitionable split
  SnnKeys keys;
  for (int t = 0; t < 30; ++t) {
    unsigned int a = 0u, bb = (unsigned int)t;
    tf2x32(0u, 42u, a, bb);
    keys.k0[t] = a; keys.k1[t] = bb;
  }

  k_pool <<<(POOL_N + 255) / 256, 256, 0, stream>>>(x, xp);
  k_conv1<<<dim3(41, 44),    256, 0, stream>>>(xp, w1, b1, h1);
  k_wt2  <<<1350, 256, 0, stream>>>(w2, w2t);
  k_conv2<<<dim3(18, 60),    256, 0, stream>>>(h1, w2t, h2p);
  k_h2fix<<<(2704000 + 255) / 256, 256, 0, stream>>>(h2p, b2, h2);
  k_wt3  <<<1350, 256, 0, stream>>>(w3, w3t);
  k_conv3<<<dim3(2, 8, 32),  256, 0, stream>>>(h2, w3t, h3p);
  k_h3fix<<<338, 256, 0, stream>>>(h3p, b3, prob);
  k_spike<<<dim3(338, 30),   256, 0, stream>>>(prob, spk, keys);
  k_fc1  <<<dim3(16, 26), dim3(8, 16), 0, stream>>>(spk, fc1w, incp);
  k_scan <<<8, 256, 0, stream>>>(incp, fc1b, cnt);
  k_final<<<1, 256, 0, stream>>>(cnt, fc2w, fc2b, out);
}

// Round 14
// 1555.305 us; speedup vs baseline: 1.2846x; 1.0048x over previous
//
#include <hip/hip_runtime.h>
#include <stdint.h>

// ---------------------------------------------------------------------------
// JAX threefry2x32 (20 rounds), matching jax/_src/prng.py
// ---------------------------------------------------------------------------
struct SnnKeys { unsigned int k0[30]; unsigned int k1[30]; };

__host__ __device__ static inline void tf2x32(unsigned int k0, unsigned int k1,
                                              unsigned int& x0, unsigned int& x1) {
  unsigned int ks2 = k0 ^ k1 ^ 0x1BD11BDAu;
#define TF_RND(r) { x0 += x1; x1 = (x1 << (r)) | (x1 >> (32 - (r))); x1 ^= x0; }
  x0 += k0; x1 += k1;
  TF_RND(13) TF_RND(15) TF_RND(26) TF_RND(6)
  x0 += k1; x1 += ks2 + 1u;
  TF_RND(17) TF_RND(29) TF_RND(16) TF_RND(24)
  x0 += ks2; x1 += k0 + 2u;
  TF_RND(13) TF_RND(15) TF_RND(26) TF_RND(6)
  x0 += k0; x1 += k1 + 3u;
  TF_RND(17) TF_RND(29) TF_RND(16) TF_RND(24)
  x0 += k1; x1 += ks2 + 4u;
  TF_RND(13) TF_RND(15) TF_RND(26) TF_RND(6)
  x0 += ks2; x1 += k0 + 5u;
#undef TF_RND
}

// ---------------------------------------------------------------------------
// Stage 0: 2x2 average pool  x(4,24,602,602) -> xp(4,24,301,301)
// ---------------------------------------------------------------------------
#define POOL_N (4 * 24 * 301 * 301)

__global__ __launch_bounds__(256) void k_pool(const float* __restrict__ x,
                                              float* __restrict__ xp) {
  int i = blockIdx.x * 256 + threadIdx.x;
  if (i >= POOL_N) return;
  int j = i % 301;
  int rest = i / 301;
  int r = rest % 301;
  int bc = rest / 301;
  const float* src = x + ((size_t)bc * 602 + 2 * r) * 602 + 2 * j;
  float2 a = *(const float2*)src;
  float2 b = *(const float2*)(src + 602);
  xp[i] = 0.25f * ((a.x + a.y) + (b.x + b.y));
}

// ---------------------------------------------------------------------------
// weight transposes: [co][ci][kd][kh][kw] -> [ci][kd][kh][kw][co]
// ---------------------------------------------------------------------------
__global__ __launch_bounds__(256) void k_wt2(const float* __restrict__ w2,
                                             float* __restrict__ w2t) {
  int i = blockIdx.x * 256 + threadIdx.x;
  if (i >= 345600) return;
  int co = i & 31;
  int rest = i >> 5;            // ci*675 + kd*225 + k
  int ci = rest / 675;
  int k675 = rest - ci * 675;
  w2t[i] = w2[((size_t)co * 16 + ci) * 675 + k675];
}

__global__ __launch_bounds__(256) void k_wt3(const float* __restrict__ w3,
                                             float* __restrict__ w3t) {
  int i = blockIdx.x * 256 + threadIdx.x;
  if (i >= 345600) return;
  int co = i & 15;
  int rest = i >> 4;            // ci*675 + kd*225 + k
  int ci = rest / 675;
  int k675 = rest - ci * 675;
  w3t[i] = w3[((size_t)co * 32 + ci) * 675 + k675];
}

// ---------------------------------------------------------------------------
// conv1 (R1 original, PERMANENT): xp(4,[1],24,301,301), w1(16,1,3,15,15), s2
// -> h1(4,16,11,144,144), relu.  grid (41 stile of 512 s, 44 b*d).
// 4 waves = 2 co-groups(8co) x 2 s-groups(256 s). Consecutive-lane b32 LDS
// reads (conflict-free); b128 restructures regress +270us (R5/R11/R12).
// ---------------------------------------------------------------------------
__global__ __launch_bounds__(256) void k_conv1(const float* __restrict__ xp,
                                               const float* __restrict__ w1,
                                               const float* __restrict__ b1,
                                               float* __restrict__ h1) {
  __shared__ alignas(16) float in_e[25 * 152];
  __shared__ alignas(16) float in_o[25 * 152];
  const int tid = threadIdx.x;
  const int wave = __builtin_amdgcn_readfirstlane(tid >> 6);
  const int lane = tid & 63;
  const int cog = wave >> 1, sg = wave & 1;
  const int cob = cog * 8;
  const int bz = blockIdx.y;
  const int b = bz / 11, d = bz % 11;
  const int s0 = blockIdx.x * 512;
  const int y0 = s0 / 144;

  int sq[4], be[4];
  bool vq[4];
#pragma unroll
  for (int q = 0; q < 4; ++q) {
    int s = s0 + sg * 256 + q * 64 + lane;
    vq[q] = (s < 20736);
    int sc = vq[q] ? s : 20735;
    int y = sc / 144, xx = sc - y * 144;
    sq[q] = s;
    be[q] = 2 * (y - y0) * 152 + xx;
  }

  float acc[8][4] = {};

  for (int kd = 0; kd < 3; ++kd) {
    __syncthreads();
    const int din = 2 * d + kd;
    const float* src = xp + (size_t)(b * 24 + din) * 90601;
    for (int i = tid; i < 25 * 301; i += 256) {
      int r = i / 301, c = i - r * 301;
      int gr = 2 * y0 + r;
      float v = (gr < 301) ? src[gr * 301 + c] : 0.0f;
      ((c & 1) ? in_o : in_e)[r * 152 + (c >> 1)] = v;
    }
    __syncthreads();
    const float* wp = w1 + cob * 675 + kd * 225;   // wp[c*675 + kh*15 + kw], uniform
    for (int kh = 0; kh < 15; ++kh) {
      float e[4][8], o[4][7];
#pragma unroll
      for (int q = 0; q < 4; ++q) {
        const float* pe = in_e + be[q] + kh * 152;
        const float* po = in_o + be[q] + kh * 152;
#pragma unroll
        for (int j = 0; j < 8; ++j) e[q][j] = pe[j];
#pragma unroll
        for (int j = 0; j < 7; ++j) o[q][j] = po[j];
      }
      const float* wk = wp + kh * 15;
#pragma unroll
      for (int j = 0; j < 8; ++j) {
#pragma unroll
        for (int c = 0; c < 8; ++c) {
          float wv = wk[c * 675 + 2 * j];
#pragma unroll
          for (int q = 0; q < 4; ++q) acc[c][q] += wv * e[q][j];
        }
      }
#pragma unroll
      for (int j = 0; j < 7; ++j) {
#pragma unroll
        for (int c = 0; c < 8; ++c) {
          float wv = wk[c * 675 + 2 * j + 1];
#pragma unroll
          for (int q = 0; q < 4; ++q) acc[c][q] += wv * o[q][j];
        }
      }
    }
  }
#pragma unroll
  for (int q = 0; q < 4; ++q) {
    if (vq[q]) {
#pragma unroll
      for (int c = 0; c < 8; ++c) {
        float v = acc[c][q] + b1[cob + c];
        h1[((size_t)(b * 16 + cob + c) * 11 + d) * 20736 + sq[q]] = fmaxf(v, 0.0f);
      }
    }
  }
}

// ---------------------------------------------------------------------------
// conv2 v4 (PERMANENT, measured 810-826us best): h1 -> 3 partials.
// linear LDS stride 76, immediate-offset b128, two barriers/stage, no
// held prefetch state (dbuf/paired variants regressed: R10/R13).
// grid (18, 60) = 1080 blocks.
// ---------------------------------------------------------------------------
__global__ __launch_bounds__(256) void k_conv2(const float* __restrict__ h1,
                                               const float* __restrict__ w2t,
                                               float* __restrict__ h2p) {
  __shared__ alignas(16) float in_e[23 * 76];
  __shared__ alignas(16) float in_o[23 * 76];
  const int tid = threadIdx.x;
  const int wave = __builtin_amdgcn_readfirstlane(tid >> 6);
  const int lane = tid & 63;
  const int cob = wave * 8;
  const int bz = blockIdx.y;
  const int cig3 = bz % 3;
  const int t5 = bz / 3;
  const int b = t5 / 5, d = t5 % 5;
  const int g0 = blockIdx.x * 64;          // gi base (gi = r*17 + g)
  const int r0 = g0 / 17;
  const int row0 = 2 * r0;

  const int gi0 = g0 + lane;
  const bool valid = (gi0 < 1105);
  const int gi = valid ? gi0 : 1104;
  const int r = gi / 17;
  const int g = gi - r * 17;
  const int lr = r - r0;                   // 0..4
  const int x0 = g * 4;

  float acc[8][4] = {};

  for (int s = 0; s < 16; ++s) {
    const int u = cig3 * 16 + s;
    const int ci = u / 3;
    const int kd = u - 3 * ci;
    __syncthreads();
    const int din = 2 * d + kd;
    const float* src = h1 + (size_t)((b * 16 + ci) * 11 + din) * 20736;
    // stage 23 input rows x 144 cols, de-interleaved even/odd (stride 76)
    for (int i = tid; i < 23 * 36; i += 256) {
      int irr = i / 36, c4 = i - irr * 36;
      int gr = row0 + irr;
      float4 v = {0.0f, 0.0f, 0.0f, 0.0f};
      if (gr < 144) v = *(const float4*)(src + gr * 144 + c4 * 4);
      *(float2*)&in_e[irr * 76 + 2 * c4] = make_float2(v.x, v.z);
      *(float2*)&in_o[irr * 76 + 2 * c4] = make_float2(v.y, v.w);
    }
    __syncthreads();
    const float* wkb = w2t + (size_t)(ci * 3 + kd) * 225 * 32 + cob;  // uniform
    const float* pe0 = in_e + 2 * lr * 76 + x0;
    const float* po0 = in_o + 2 * lr * 76 + x0;
#pragma unroll 5
    for (int kh = 0; kh < 15; ++kh) {
      float4 e0 = *(const float4*)(pe0 + kh * 76);
      float4 e1 = *(const float4*)(pe0 + kh * 76 + 4);
      float4 e2 = *(const float4*)(pe0 + kh * 76 + 8);
      float4 o0 = *(const float4*)(po0 + kh * 76);
      float4 o1 = *(const float4*)(po0 + kh * 76 + 4);
      float4 o2 = *(const float4*)(po0 + kh * 76 + 8);
      float E[12] = {e0.x, e0.y, e0.z, e0.w, e1.x, e1.y, e1.z, e1.w,
                     e2.x, e2.y, e2.z, e2.w};
      float O[12] = {o0.x, o0.y, o0.z, o0.w, o1.x, o1.y, o1.z, o1.w,
                     o2.x, o2.y, o2.z, o2.w};
      const float* wk = wkb + kh * 480;     // 15 taps * 32 co
#pragma unroll
      for (int m = 0; m < 8; ++m) {         // even kw = 2m
#pragma unroll
        for (int c = 0; c < 8; ++c) {
          float wv = wk[m * 64 + c];
#pragma unroll
          for (int u2 = 0; u2 < 4; ++u2) acc[c][u2] += wv * E[m + u2];
        }
      }
#pragma unroll
      for (int m = 0; m < 7; ++m) {         // odd kw = 2m+1
#pragma unroll
        for (int c = 0; c < 8; ++c) {
          float wv = wk[m * 64 + 32 + c];
#pragma unroll
          for (int u2 = 0; u2 < 4; ++u2) acc[c][u2] += wv * O[m + u2];
        }
      }
    }
  }
  if (valid) {
    float* dst = h2p + (size_t)cig3 * 2704000 +
                 ((size_t)(b * 32 + cob) * 5 + d) * 4225 + r * 65 + x0;
#pragma unroll
    for (int c = 0; c < 8; ++c) {
#pragma unroll
      for (int u = 0; u < 4; ++u) {
        if (x0 + u < 65) dst[(size_t)c * 21125 + u] = acc[c][u];
      }
    }
  }
}

// combine conv2 partials (3) + bias + relu
__global__ __launch_bounds__(256) void k_h2fix(const float* __restrict__ p,
                                               const float* __restrict__ b2,
                                               float* __restrict__ h2) {
  int i = blockIdx.x * 256 + threadIdx.x;
  if (i >= 2704000) return;
  int co = (i / 21125) & 31;               // 21125 = 5*65*65
  float v = p[i] + p[2704000 + i] + p[5408000 + i] + b2[co];
  h2[i] = fmaxf(v, 0.0f);
}

// ---------------------------------------------------------------------------
// conv3: h2(4,32,5,65,65), w3t[ci][kd][k][16] -> 32 ci-partials
// Flattened-s: plane 26*26=676 per (b,d). grid (2 stile of 512, 8 planes, 32 ci).
// 4 waves = 2 co-groups(8co) x 2 s-groups(256 s). 512 blocks (2/CU).
// ---------------------------------------------------------------------------
__global__ __launch_bounds__(256) void k_conv3(const float* __restrict__ h2,
                                               const float* __restrict__ w3t,
                                               float* __restrict__ h3p) {
  __shared__ alignas(16) float in_e[55 * 36];
  __shared__ alignas(16) float in_o[55 * 36];
  const int tid = threadIdx.x;
  const int wave = __builtin_amdgcn_readfirstlane(tid >> 6);
  const int lane = tid & 63;
  const int cog = wave >> 1, sg = wave & 1;
  const int cob = cog * 8;
  const int bz = blockIdx.y;               // b*2 + d
  const int b = bz >> 1, d = bz & 1;
  const int ci = blockIdx.z;               // 0..31
  const int s0 = blockIdx.x * 512;
  const int y0 = s0 / 26;

  int sq[4], be[4];
  bool vq[4];
#pragma unroll
  for (int q = 0; q < 4; ++q) {
    int s = s0 + sg * 256 + q * 64 + lane;
    vq[q] = (s < 676);
    int sc = vq[q] ? s : 675;
    int y = sc / 26, xx = sc - y * 26;
    sq[q] = s;
    be[q] = 2 * (y - y0) * 36 + xx;
  }

  float acc[8][4] = {};

  for (int kd = 0; kd < 3; ++kd) {
    __syncthreads();
    const int din = 2 * d + kd;
    const float* src = h2 + (size_t)((b * 32 + ci) * 5 + din) * 4225;
    for (int i = tid; i < 55 * 65; i += 256) {
      int r = i / 65, c = i - r * 65;
      int gr = 2 * y0 + r;
      float v = (gr < 65) ? src[gr * 65 + c] : 0.0f;
      ((c & 1) ? in_o : in_e)[r * 36 + (c >> 1)] = v;
    }
    __syncthreads();
    const float* wkbase = w3t + (size_t)(ci * 3 + kd) * 225 * 16 + cob;  // uniform
    for (int kh = 0; kh < 15; ++kh) {
      float e[4][8], o[4][7];
#pragma unroll
      for (int q = 0; q < 4; ++q) {
        const float* pe = in_e + be[q] + kh * 36;
        const float* po = in_o + be[q] + kh * 36;
#pragma unroll
        for (int j = 0; j < 8; ++j) e[q][j] = pe[j];
#pragma unroll
        for (int j = 0; j < 7; ++j) o[q][j] = po[j];
      }
      const float* wr = wkbase + kh * 15 * 16;
#pragma unroll
      for (int j = 0; j < 8; ++j) {
#pragma unroll
        for (int c = 0; c < 8; ++c) {
          float wv = wr[(2 * j) * 16 + c];
#pragma unroll
          for (int q = 0; q < 4; ++q) acc[c][q] += wv * e[q][j];
        }
      }
#pragma unroll
      for (int j = 0; j < 7; ++j) {
#pragma unroll
        for (int c = 0; c < 8; ++c) {
          float wv = wr[(2 * j + 1) * 16 + c];
#pragma unroll
          for (int q = 0; q < 4; ++q) acc[c][q] += wv * o[q][j];
        }
      }
    }
  }
#pragma unroll
  for (int q = 0; q < 4; ++q) {
    if (vq[q]) {
#pragma unroll
      for (int c = 0; c < 8; ++c) {
        h3p[(size_t)ci * 86528 +
            ((size_t)(b * 16 + cob + c) * 2 + d) * 676 + sq[q]] = acc[c][q];
      }
    }
  }
}

// fold 32 conv3 partials + bias + relu -> prob = 0.5*x
__global__ __launch_bounds__(256) void k_h3fix(const float* __restrict__ h3p,
                                               const float* __restrict__ b3,
                                               float* __restrict__ prob) {
  int p = blockIdx.x * 256 + threadIdx.x;
  if (p >= 86528) return;
  int co = (p % 21632) / 1352;             // 1352 = 2*26*26
  float x = b3[co];
  for (int g = 0; g < 32; ++g) x += h3p[(size_t)g * 86528 + p];
  prob[p] = 0.5f * fmaxf(x, 0.0f);
}

// ---------------------------------------------------------------------------
// spikes: r = threefry-uniform; spk = (prob > r)
// grid (338, 30) block 256
// ---------------------------------------------------------------------------
__global__ __launch_bounds__(256) void k_spike(const float* __restrict__ prob,
                                               float* __restrict__ spk,
                                               SnnKeys keys) {
  int p = blockIdx.x * 256 + threadIdx.x;   // < 86528
  int t = blockIdx.y;
  float pr = prob[p];
  unsigned int x0 = 0u, x1 = (unsigned int)p;
  tf2x32(keys.k0[t], keys.k1[t], x0, x1);
  unsigned int bits = x0 ^ x1;              // partitionable 32-bit path
  float r = __uint_as_float((bits >> 9) | 0x3f800000u) - 1.0f;
  spk[(size_t)t * 86528 + p] = (pr > r) ? 1.0f : 0.0f;
}

// ---------------------------------------------------------------------------
// fc1 GEMM: inc_part[kc][m=(t*4+b)][n] = sum_k spk[m][k]*fc1_w[n][k]  (K split 26x832)
// grid (16 nt, 26 kc), block (8,16)=128. thread tile 8m x 4n.
// ---------------------------------------------------------------------------
__global__ __launch_bounds__(128) void k_fc1(const float* __restrict__ spk,
                                             const float* __restrict__ fc1w,
                                             float* __restrict__ incp) {
  __shared__ alignas(16) float slds[16][128];
  __shared__ alignas(16) float wlds[16][32];
  const int tx = threadIdx.x;               // 0..7
  const int ty = threadIdx.y;               // 0..15
  const int tid = ty * 8 + tx;
  const int nt = blockIdx.x;                // 0..15
  const int kc = blockIdx.y;                // 0..25
  const int k0base = kc * 832;

  float acc[8][4];
#pragma unroll
  for (int mi = 0; mi < 8; ++mi)
#pragma unroll
    for (int ni = 0; ni < 4; ++ni) acc[mi][ni] = 0.0f;

  for (int kb = 0; kb < 832; kb += 16) {
    const int k0 = k0base + kb;
    __syncthreads();
    {
      int m = tid;  // 0..127
      float4 v[4] = {{0,0,0,0},{0,0,0,0},{0,0,0,0},{0,0,0,0}};
      if (m < 120) {
        const float4* s = (const float4*)(spk + (size_t)m * 21632 + k0);
        v[0] = s[0]; v[1] = s[1]; v[2] = s[2]; v[3] = s[3];
      }
#pragma unroll
      for (int q = 0; q < 4; ++q) {
        slds[4 * q + 0][m] = v[q].x;
        slds[4 * q + 1][m] = v[q].y;
        slds[4 * q + 2][m] = v[q].z;
        slds[4 * q + 3][m] = v[q].w;
      }
    }
    for (int e = tid; e < 512; e += 128) {
      int n = e >> 4, kk = e & 15;
      wlds[kk][n] = fc1w[(size_t)(nt * 32 + n) * 21632 + k0 + kk];
    }
    __syncthreads();
#pragma unroll
    for (int kk = 0; kk < 16; ++kk) {
      const float4 wv = *(const float4*)&wlds[kk][tx * 4];
      const float4 s0 = *(const float4*)&slds[kk][ty * 8];
      const float4 s1 = *(const float4*)&slds[kk][ty * 8 + 4];
      float sv[8] = {s0.x, s0.y, s0.z, s0.w, s1.x, s1.y, s1.z, s1.w};
      float wz[4] = {wv.x, wv.y, wv.z, wv.w};
#pragma unroll
      for (int mi = 0; mi < 8; ++mi)
#pragma unroll
        for (int ni = 0; ni < 4; ++ni) acc[mi][ni] += sv[mi] * wz[ni];
    }
  }
#pragma unroll
  for (int mi = 0; mi < 8; ++mi) {
    int m = ty * 8 + mi;
    if (m < 120) {
      float4 o = {acc[mi][0], acc[mi][1], acc[mi][2], acc[mi][3]};
      *(float4*)&incp[((size_t)kc * 120 + m) * 512 + nt * 32 + tx * 4] = o;
    }
  }
}

// ---------------------------------------------------------------------------
// reduce 26 K-partials -> inc[120][512] (parallel, 240 blocks)
// ---------------------------------------------------------------------------
__global__ __launch_bounds__(256) void k_ksum(const float* __restrict__ incp,
                                              float* __restrict__ inc) {
  int i = blockIdx.x * 256 + threadIdx.x;   // < 61440
  float s = 0.0f;
  for (int kc = 0; kc < 26; ++kc) s += incp[(size_t)kc * 61440 + i];
  inc[i] = s;
}

// ---------------------------------------------------------------------------
// sequential membrane scan per (b,n): fire/reset, emit spike counts
// ---------------------------------------------------------------------------
__global__ __launch_bounds__(256) void k_scan(const float* __restrict__ inc,
                                              const float* __restrict__ fc1b,
                                              float* __restrict__ cnt) {
  int i = blockIdx.x * 256 + threadIdx.x;   // 0..2047
  int b = i >> 9, n = i & 511;
  float bias = fc1b[n];
  float m0 = 0.0f, c = 0.0f;
  for (int t = 0; t < 30; ++t) {
    int m = t * 4 + b;
    float s = bias + inc[(size_t)m * 512 + n];
    m0 += s;
    if (m0 > 1.0f) { c += 1.0f; m0 = 0.0f; }
  }
  cnt[i] = c;
}

// ---------------------------------------------------------------------------
// m1[b][o] = 30*fc2_b[o] + sum_n cnt[b][n]*fc2_w[o][n]
// ---------------------------------------------------------------------------
__global__ __launch_bounds__(256) void k_final(const float* __restrict__ cnt,
                                               const float* __restrict__ fc2w,
                                               const float* __restrict__ fc2b,
                                               float* __restrict__ out) {
  int o = threadIdx.x;
  if (o >= 216) return;
  int b = o / 54, oo = o - b * 54;
  const float* w = fc2w + (size_t)oo * 512;
  const float* c = cnt + (size_t)b * 512;
  float s = 0.0f;
  for (int n = 0; n < 512; ++n) s += c[n] * w[n];
  out[o] = s + 30.0f * fc2b[oo];
}

// ---------------------------------------------------------------------------
extern "C" void kernel_launch(void* const* d_in, const int* in_sizes, int n_in,
                              void* d_out, int out_size, void* d_ws, size_t ws_size,
                              hipStream_t stream) {
  (void)in_sizes; (void)n_in; (void)out_size; (void)ws_size;
  const float* x    = (const float*)d_in[0];
  const float* w1   = (const float*)d_in[1];
  const float* b1   = (const float*)d_in[2];
  const float* w2   = (const float*)d_in[3];
  const float* b2   = (const float*)d_in[4];
  const float* w3   = (const float*)d_in[5];
  const float* b3   = (const float*)d_in[6];
  const float* fc1w = (const float*)d_in[7];
  const float* fc1b = (const float*)d_in[8];
  const float* fc2w = (const float*)d_in[9];
  const float* fc2b = (const float*)d_in[10];
  float* out = (float*)d_out;
  float* ws  = (float*)d_ws;

  // workspace layout (floats); peak = xp+h1 = 23,295,840 fl = 93.2 MB (unchanged)
  float* xp   = ws;                       // [0 .. 8,697,696)            dead after conv1
  float* h1   = ws + 8697696;             // [8,697,696 .. 23,295,840)   dead after conv2
  float* w2t  = ws + 8112000;             // 345,600 in dead-xp tail [8,112,000..8,457,600)
  float* h2p  = ws;                       // 3 x 2,704,000 = [0 .. 8,112,000)
  float* h2   = ws + 8697696;             // [8,697,696 .. 11,401,696)  (dead h1 region)
  float* w3t  = ws;                       // 345,600 (in dead h2p; written after h2fix)
  float* h3p  = ws + 11401696;            // 32 x 86,528 = [11,401,696 .. 14,170,592)
  float* prob = ws + 14170592;            // 86,528 -> 14,257,120
  float* spk  = ws + 14257120;            // 2,595,840 -> 16,852,960
  float* incp = ws + 16852960;            // 26 x 61,440 -> 18,450,400
  float* cnt  = ws + 18450400;            // 2,048 -> 18,452,448
  float* inc  = ws + 18452448;            // 61,440 (end 18,513,888 < 23,295,840)

  // host-side threefry: seed 42 -> key (0,42); partitionable split
  SnnKeys keys;
  for (int t = 0; t < 30; ++t) {
    unsigned int a = 0u, bb = (unsigned int)t;
    tf2x32(0u, 42u, a, bb);
    keys.k0[t] = a; keys.k1[t] = bb;
  }

  k_pool <<<(POOL_N + 255) / 256, 256, 0, stream>>>(x, xp);
  k_conv1<<<dim3(41, 44),    256, 0, stream>>>(xp, w1, b1, h1);
  k_wt2  <<<1350, 256, 0, stream>>>(w2, w2t);
  k_conv2<<<dim3(18, 60),    256, 0, stream>>>(h1, w2t, h2p);
  k_h2fix<<<(2704000 + 255) / 256, 256, 0, stream>>>(h2p, b2, h2);
  k_wt3  <<<1350, 256, 0, stream>>>(w3, w3t);
  k_conv3<<<dim3(2, 8, 32),  256, 0, stream>>>(h2, w3t, h3p);
  k_h3fix<<<338, 256, 0, stream>>>(h3p, b3, prob);
  k_spike<<<dim3(338, 30),   256, 0, stream>>>(prob, spk, keys);
  k_fc1  <<<dim3(16, 26), dim3(8, 16), 0, stream>>>(spk, fc1w, incp);
  k_ksum <<<240, 256, 0, stream>>>(incp, inc);
  k_scan <<<8, 256, 0, stream>>>(inc, fc1b, cnt);
  k_final<<<1, 256, 0, stream>>>(cnt, fc2w, fc2b, out);
}